// Round 4
// baseline (255.742 us; speedup 1.0000x reference)
//
#include <hip/hip_runtime.h>

#define NN 10000
#define DIN 128
#define DOUT 256
static constexpr float BN_EPS = 1e-5f;

// ---------------------------------------------------------------------------
// Kernel H: per-block LDS histogram of in-degrees
// ---------------------------------------------------------------------------
__global__ __launch_bounds__(256) void hist_k(const int* __restrict__ ei,
                                              int* __restrict__ deg, int E) {
    __shared__ int hist[NN];
    const int tid = threadIdx.x;
    for (int i = tid; i < NN; i += 256) hist[i] = 0;
    __syncthreads();
    for (int e = blockIdx.x * 256 + tid; e < E; e += gridDim.x * 256) {
        atomicAdd(&hist[ei[E + e]], 1);
    }
    __syncthreads();
    for (int i = tid; i < NN; i += 256) {
        const int v = hist[i];
        if (v) atomicAdd(&deg[i], v);
    }
}

// ---------------------------------------------------------------------------
// Kernel S: single-block exclusive scan (10000 -> offsets[10001], cursor copy)
// ---------------------------------------------------------------------------
__global__ __launch_bounds__(1024) void scan_k(const int* __restrict__ deg,
                                               int* __restrict__ offsets,
                                               int* __restrict__ cursor) {
    __shared__ int part[1024];
    const int t = threadIdx.x;
    const int base = t * 10;
    int local[10];
    int s = 0;
#pragma unroll
    for (int k = 0; k < 10; ++k) {
        const int i = base + k;
        const int v = (i < NN) ? deg[i] : 0;
        local[k] = s;
        s += v;
    }
    part[t] = s;
    __syncthreads();
    for (int off = 1; off < 1024; off <<= 1) {
        int v = 0;
        if (t >= off) v = part[t - off];
        __syncthreads();
        if (t >= off) part[t] += v;
        __syncthreads();
    }
    const int prefix = (t == 0) ? 0 : part[t - 1];
#pragma unroll
    for (int k = 0; k < 10; ++k) {
        const int i = base + k;
        if (i < NN) {
            const int o = prefix + local[k];
            offsets[i] = o;
            cursor[i] = o;
        }
    }
    if (t == 1023) offsets[NN] = part[1023];
}

// ---------------------------------------------------------------------------
// Kernel F: CSR fill — edge_src[pos] = src, pos from per-dst cursor
// ---------------------------------------------------------------------------
__global__ __launch_bounds__(256) void fill_k(const int* __restrict__ ei,
                                              int* __restrict__ cursor,
                                              int* __restrict__ edge_src,
                                              int E) {
    for (int e = blockIdx.x * 256 + threadIdx.x; e < E;
         e += gridDim.x * 256) {
        const int src = ei[e];
        const int dst = ei[E + e];
        const int pos = atomicAdd(&cursor[dst], 1);
        edge_src[pos] = src;
    }
}

// ---------------------------------------------------------------------------
// Kernel A: gather-aggregate. Half-wave (32 lanes) per node, lane = 4 dims.
// 4-deep edge unroll for gather-latency hiding. 10000 = 1250 * 8 exact.
// ---------------------------------------------------------------------------
__global__ __launch_bounds__(256) void aggregate_k(
    const float* __restrict__ x, const int* __restrict__ offsets,
    const int* __restrict__ edge_src, float* __restrict__ xin) {
    const int node = blockIdx.x * 8 + (threadIdx.x >> 5);
    const int col = (threadIdx.x & 31) << 2;  // 0..124
    const int beg = offsets[node];
    const int end = offsets[node + 1];

    float4 a0 = make_float4(0.f, 0.f, 0.f, 0.f);
    float4 a1 = a0, a2 = a0, a3 = a0;
    int j = beg;
    for (; j + 3 < end; j += 4) {
        const int s0 = edge_src[j + 0];
        const int s1 = edge_src[j + 1];
        const int s2 = edge_src[j + 2];
        const int s3 = edge_src[j + 3];
        const float4 v0 = *reinterpret_cast<const float4*>(x + (size_t)s0 * DIN + col);
        const float4 v1 = *reinterpret_cast<const float4*>(x + (size_t)s1 * DIN + col);
        const float4 v2 = *reinterpret_cast<const float4*>(x + (size_t)s2 * DIN + col);
        const float4 v3 = *reinterpret_cast<const float4*>(x + (size_t)s3 * DIN + col);
        a0.x += v0.x; a0.y += v0.y; a0.z += v0.z; a0.w += v0.w;
        a1.x += v1.x; a1.y += v1.y; a1.z += v1.z; a1.w += v1.w;
        a2.x += v2.x; a2.y += v2.y; a2.z += v2.z; a2.w += v2.w;
        a3.x += v3.x; a3.y += v3.y; a3.z += v3.z; a3.w += v3.w;
    }
    for (; j < end; ++j) {
        const int s0 = edge_src[j];
        const float4 v0 = *reinterpret_cast<const float4*>(x + (size_t)s0 * DIN + col);
        a0.x += v0.x; a0.y += v0.y; a0.z += v0.z; a0.w += v0.w;
    }
    const float4 xv = *reinterpret_cast<const float4*>(x + (size_t)node * DIN + col);
    float4 r;
    r.x = xv.x + a0.x + a1.x + a2.x + a3.x;
    r.y = xv.y + a0.y + a1.y + a2.y + a3.y;
    r.z = xv.z + a0.z + a1.z + a2.z + a3.z;
    r.w = xv.w + a0.w + a1.w + a2.w + a3.w;
    *reinterpret_cast<float4*>(xin + (size_t)node * DIN + col) = r;
}

// ---------------------------------------------------------------------------
// Kernel 2: h1 = xin @ W1 + b1, plus BN1 sums.
// TM=8 rows/block; 256 thr = 8 row-groups x 32 col-threads; thread = 1 row x 8 cols.
// ---------------------------------------------------------------------------
__global__ __launch_bounds__(256) void gemm1_k(
    const float* __restrict__ xin, const float* __restrict__ W1,
    const float* __restrict__ b1, float* __restrict__ h1,
    float* __restrict__ sum1, float* __restrict__ sq1) {
    __shared__ float xs[8][DIN];     // 4 KB
    __shared__ float red[8][DOUT];   // 8 KB
    const int row0 = blockIdx.x * 8;
    const int tid = threadIdx.x;
    const int g = tid >> 5;          // row-group 0..7
    const int c = tid & 31;          // col-thread 0..31 -> cols 8c..8c+7

    // stage 8 rows of xin (1024 floats = 256 float4)
    reinterpret_cast<float4*>(&xs[0][0])[tid] =
        reinterpret_cast<const float4*>(xin + (size_t)row0 * DIN)[tid];
    __syncthreads();

    const float4* w4 = reinterpret_cast<const float4*>(W1) + 2 * c;
    float4 aLo = reinterpret_cast<const float4*>(b1)[2 * c];
    float4 aHi = reinterpret_cast<const float4*>(b1)[2 * c + 1];

    for (int k = 0; k < DIN; k += 4) {
        const float4 xv = *reinterpret_cast<const float4*>(&xs[g][k]);
        const float xk[4] = {xv.x, xv.y, xv.z, xv.w};
#pragma unroll
        for (int kk = 0; kk < 4; ++kk) {
            const float4 wLo = w4[(size_t)(k + kk) * (DOUT / 4)];
            const float4 wHi = w4[(size_t)(k + kk) * (DOUT / 4) + 1];
            const float xs_ = xk[kk];
            aLo.x = fmaf(xs_, wLo.x, aLo.x);
            aLo.y = fmaf(xs_, wLo.y, aLo.y);
            aLo.z = fmaf(xs_, wLo.z, aLo.z);
            aLo.w = fmaf(xs_, wLo.w, aLo.w);
            aHi.x = fmaf(xs_, wHi.x, aHi.x);
            aHi.y = fmaf(xs_, wHi.y, aHi.y);
            aHi.z = fmaf(xs_, wHi.z, aHi.z);
            aHi.w = fmaf(xs_, wHi.w, aHi.w);
        }
    }

    // store h1 row
    float4* h4 = reinterpret_cast<float4*>(h1 + (size_t)(row0 + g) * DOUT);
    h4[2 * c] = aLo;
    h4[2 * c + 1] = aHi;

    // block-reduce BN sums: s-pass then sq-pass through red
    __syncthreads();
    {
        float4* r4 = reinterpret_cast<float4*>(&red[g][0]);
        r4[2 * c] = aLo;
        r4[2 * c + 1] = aHi;
    }
    __syncthreads();
    {
        float s = 0.f;
#pragma unroll
        for (int gg = 0; gg < 8; ++gg) s += red[gg][tid];
        atomicAdd(&sum1[tid], s);
    }
    __syncthreads();
    {
        float4 qLo, qHi;
        qLo.x = aLo.x * aLo.x; qLo.y = aLo.y * aLo.y;
        qLo.z = aLo.z * aLo.z; qLo.w = aLo.w * aLo.w;
        qHi.x = aHi.x * aHi.x; qHi.y = aHi.y * aHi.y;
        qHi.z = aHi.z * aHi.z; qHi.w = aHi.w * aHi.w;
        float4* r4 = reinterpret_cast<float4*>(&red[g][0]);
        r4[2 * c] = qLo;
        r4[2 * c + 1] = qHi;
    }
    __syncthreads();
    {
        float s = 0.f;
#pragma unroll
        for (int gg = 0; gg < 8; ++gg) s += red[gg][tid];
        atomicAdd(&sq1[tid], s);
    }
}

// ---------------------------------------------------------------------------
// Kernel 3: BN finalize -> per-feature scale/shift
// ---------------------------------------------------------------------------
__global__ void bn_final_k(const float* __restrict__ sum,
                           const float* __restrict__ sq,
                           const float* __restrict__ gamma,
                           const float* __restrict__ beta,
                           float* __restrict__ scale,
                           float* __restrict__ shift) {
    const int j = threadIdx.x;  // 256
    const float nInv = 1.0f / (float)NN;
    const float mean = sum[j] * nInv;
    const float var = sq[j] * nInv - mean * mean;
    const float sc = gamma[j] * rsqrtf(var + BN_EPS);
    scale[j] = sc;
    shift[j] = beta[j] - mean * sc;
}

// ---------------------------------------------------------------------------
// Kernel 4: h2 = relu(bn1(h1)) @ W2 + b2, plus BN2 sums. Same structure, K=256.
// ---------------------------------------------------------------------------
__global__ __launch_bounds__(256) void gemm2_k(
    const float* __restrict__ h1, const float* __restrict__ scale1,
    const float* __restrict__ shift1, const float* __restrict__ W2,
    const float* __restrict__ b2, float* __restrict__ h2,
    float* __restrict__ sum2, float* __restrict__ sq2) {
    __shared__ float gs[8][DOUT];    // 8 KB
    __shared__ float red[8][DOUT];   // 8 KB
    const int row0 = blockIdx.x * 8;
    const int tid = threadIdx.x;
    const int g = tid >> 5;
    const int c = tid & 31;

    // stage 8 rows of relu(bn1(h1)) : 2048 floats = 512 float4
    {
        const float4* s4 = reinterpret_cast<const float4*>(scale1);
        const float4* f4 = reinterpret_cast<const float4*>(shift1);
        const float4* src = reinterpret_cast<const float4*>(h1 + (size_t)row0 * DOUT);
        float4* dst = reinterpret_cast<float4*>(&gs[0][0]);
#pragma unroll
        for (int i = 0; i < 2; ++i) {
            const int u = tid + 256 * i;
            const int k4 = u & 63;
            const float4 h = src[u];
            const float4 sc = s4[k4];
            const float4 sh = f4[k4];
            float4 gv;
            gv.x = fmaxf(fmaf(h.x, sc.x, sh.x), 0.f);
            gv.y = fmaxf(fmaf(h.y, sc.y, sh.y), 0.f);
            gv.z = fmaxf(fmaf(h.z, sc.z, sh.z), 0.f);
            gv.w = fmaxf(fmaf(h.w, sc.w, sh.w), 0.f);
            dst[u] = gv;
        }
    }
    __syncthreads();

    const float4* w4 = reinterpret_cast<const float4*>(W2) + 2 * c;
    float4 aLo = reinterpret_cast<const float4*>(b2)[2 * c];
    float4 aHi = reinterpret_cast<const float4*>(b2)[2 * c + 1];

    for (int k = 0; k < DOUT; k += 4) {
        const float4 xv = *reinterpret_cast<const float4*>(&gs[g][k]);
        const float xk[4] = {xv.x, xv.y, xv.z, xv.w};
#pragma unroll
        for (int kk = 0; kk < 4; ++kk) {
            const float4 wLo = w4[(size_t)(k + kk) * (DOUT / 4)];
            const float4 wHi = w4[(size_t)(k + kk) * (DOUT / 4) + 1];
            const float xs_ = xk[kk];
            aLo.x = fmaf(xs_, wLo.x, aLo.x);
            aLo.y = fmaf(xs_, wLo.y, aLo.y);
            aLo.z = fmaf(xs_, wLo.z, aLo.z);
            aLo.w = fmaf(xs_, wLo.w, aLo.w);
            aHi.x = fmaf(xs_, wHi.x, aHi.x);
            aHi.y = fmaf(xs_, wHi.y, aHi.y);
            aHi.z = fmaf(xs_, wHi.z, aHi.z);
            aHi.w = fmaf(xs_, wHi.w, aHi.w);
        }
    }

    float4* h4 = reinterpret_cast<float4*>(h2 + (size_t)(row0 + g) * DOUT);
    h4[2 * c] = aLo;
    h4[2 * c + 1] = aHi;

    __syncthreads();
    {
        float4* r4 = reinterpret_cast<float4*>(&red[g][0]);
        r4[2 * c] = aLo;
        r4[2 * c + 1] = aHi;
    }
    __syncthreads();
    {
        float s = 0.f;
#pragma unroll
        for (int gg = 0; gg < 8; ++gg) s += red[gg][tid];
        atomicAdd(&sum2[tid], s);
    }
    __syncthreads();
    {
        float4 qLo, qHi;
        qLo.x = aLo.x * aLo.x; qLo.y = aLo.y * aLo.y;
        qLo.z = aLo.z * aLo.z; qLo.w = aLo.w * aLo.w;
        qHi.x = aHi.x * aHi.x; qHi.y = aHi.y * aHi.y;
        qHi.z = aHi.z * aHi.z; qHi.w = aHi.w * aHi.w;
        float4* r4 = reinterpret_cast<float4*>(&red[g][0]);
        r4[2 * c] = qLo;
        r4[2 * c + 1] = qHi;
    }
    __syncthreads();
    {
        float s = 0.f;
#pragma unroll
        for (int gg = 0; gg < 8; ++gg) s += red[gg][tid];
        atomicAdd(&sq2[tid], s);
    }
}

// ---------------------------------------------------------------------------
// Kernel 5: out = relu(bn2(h2)), float4
// ---------------------------------------------------------------------------
__global__ __launch_bounds__(256) void bn_relu_out_k(
    const float* __restrict__ h2, const float* __restrict__ scale2,
    const float* __restrict__ shift2, float* __restrict__ out) {
    const int u = blockIdx.x * 256 + threadIdx.x;  // float4 index
    if (u < NN * DOUT / 4) {
        const int k4 = u & 63;
        const float4 h = reinterpret_cast<const float4*>(h2)[u];
        const float4 sc = reinterpret_cast<const float4*>(scale2)[k4];
        const float4 sh = reinterpret_cast<const float4*>(shift2)[k4];
        float4 g;
        g.x = fmaxf(fmaf(h.x, sc.x, sh.x), 0.f);
        g.y = fmaxf(fmaf(h.y, sc.y, sh.y), 0.f);
        g.z = fmaxf(fmaf(h.z, sc.z, sh.z), 0.f);
        g.w = fmaxf(fmaf(h.w, sc.w, sh.w), 0.f);
        reinterpret_cast<float4*>(out)[u] = g;
    }
}

// ---------------------------------------------------------------------------
extern "C" void kernel_launch(void* const* d_in, const int* in_sizes, int n_in,
                              void* d_out, int out_size, void* d_ws,
                              size_t ws_size, hipStream_t stream) {
    const float* x      = (const float*)d_in[0];
    const int*   ei     = (const int*)d_in[1];
    const float* W1     = (const float*)d_in[2];
    const float* b1     = (const float*)d_in[3];
    const float* gamma1 = (const float*)d_in[4];
    const float* beta1  = (const float*)d_in[5];
    const float* W2     = (const float*)d_in[6];
    const float* b2     = (const float*)d_in[7];
    const float* gamma2 = (const float*)d_in[8];
    const float* beta2  = (const float*)d_in[9];
    const int E = in_sizes[1] / 2;

    char* w = (char*)d_ws;
    float* stats   = (float*)w;
    float* sum1    = stats + 0;
    float* sq1     = stats + 256;
    float* scale1  = stats + 512;
    float* shift1  = stats + 768;
    float* sum2    = stats + 1024;
    float* sq2     = stats + 1280;
    float* scale2  = stats + 1536;
    float* shift2  = stats + 1792;
    int* deg       = (int*)(w + 8192);
    int* offsets   = (int*)(w + 8192 + 40064);
    int* cursor    = (int*)(w + 8192 + 2 * 40064);
    int* edge_src  = (int*)(w + 8192 + 3 * 40064);
    float* xin     = (float*)(w + 8192 + 3 * 40064 + (size_t)E * 4);
    float* h1      = xin + (size_t)NN * DIN;
    float* h2      = h1 + (size_t)NN * DOUT;
    float* out     = (float*)d_out;

    hipMemsetAsync(d_ws, 0, 8192 + 40064, stream);

    hist_k<<<80, 256, 0, stream>>>(ei, deg, E);
    scan_k<<<1, 1024, 0, stream>>>(deg, offsets, cursor);
    fill_k<<<2048, 256, 0, stream>>>(ei, cursor, edge_src, E);
    aggregate_k<<<NN / 8, 256, 0, stream>>>(x, offsets, edge_src, xin);
    gemm1_k<<<NN / 8, 256, 0, stream>>>(xin, W1, b1, h1, sum1, sq1);
    bn_final_k<<<1, 256, 0, stream>>>(sum1, sq1, gamma1, beta1, scale1, shift1);
    gemm2_k<<<NN / 8, 256, 0, stream>>>(h1, scale1, shift1, W2, b2, h2,
                                        sum2, sq2);
    bn_final_k<<<1, 256, 0, stream>>>(sum2, sq2, gamma2, beta2, scale2, shift2);
    bn_relu_out_k<<<NN * DOUT / 4 / 256, 256, 0, stream>>>(h2, scale2,
                                                           shift2, out);
}

// Round 5
// 162.144 us; speedup vs baseline: 1.5773x; 1.5773x over previous
//
#include <hip/hip_runtime.h>

#define NN 10000
#define DIN 128
#define DOUT 256
static constexpr float BN_EPS = 1e-5f;

// ---------------------------------------------------------------------------
// Kernel H: per-block LDS histogram of in-degrees
// ---------------------------------------------------------------------------
__global__ __launch_bounds__(256) void hist_k(const int* __restrict__ ei,
                                              int* __restrict__ deg, int E) {
    __shared__ int hist[NN];
    const int tid = threadIdx.x;
    for (int i = tid; i < NN; i += 256) hist[i] = 0;
    __syncthreads();
    for (int e = blockIdx.x * 256 + tid; e < E; e += gridDim.x * 256) {
        atomicAdd(&hist[ei[E + e]], 1);
    }
    __syncthreads();
    for (int i = tid; i < NN; i += 256) {
        const int v = hist[i];
        if (v) atomicAdd(&deg[i], v);
    }
}

// ---------------------------------------------------------------------------
// Kernel S: single-block exclusive scan (10000 -> offsets[10001], cursor copy)
// ---------------------------------------------------------------------------
__global__ __launch_bounds__(1024) void scan_k(const int* __restrict__ deg,
                                               int* __restrict__ offsets,
                                               int* __restrict__ cursor) {
    __shared__ int part[1024];
    const int t = threadIdx.x;
    const int base = t * 10;
    int local[10];
    int s = 0;
#pragma unroll
    for (int k = 0; k < 10; ++k) {
        const int i = base + k;
        const int v = (i < NN) ? deg[i] : 0;
        local[k] = s;
        s += v;
    }
    part[t] = s;
    __syncthreads();
    for (int off = 1; off < 1024; off <<= 1) {
        int v = 0;
        if (t >= off) v = part[t - off];
        __syncthreads();
        if (t >= off) part[t] += v;
        __syncthreads();
    }
    const int prefix = (t == 0) ? 0 : part[t - 1];
#pragma unroll
    for (int k = 0; k < 10; ++k) {
        const int i = base + k;
        if (i < NN) {
            const int o = prefix + local[k];
            offsets[i] = o;
            cursor[i] = o;
        }
    }
    if (t == 1023) offsets[NN] = part[1023];
}

// ---------------------------------------------------------------------------
// Kernel F: CSR fill — edge_src[pos] = src, pos from per-dst cursor
// ---------------------------------------------------------------------------
__global__ __launch_bounds__(256) void fill_k(const int* __restrict__ ei,
                                              int* __restrict__ cursor,
                                              int* __restrict__ edge_src,
                                              int E) {
    for (int e = blockIdx.x * 256 + threadIdx.x; e < E;
         e += gridDim.x * 256) {
        const int src = ei[e];
        const int dst = ei[E + e];
        const int pos = atomicAdd(&cursor[dst], 1);
        edge_src[pos] = src;
    }
}

// ---------------------------------------------------------------------------
// Kernel A: gather-aggregate. Half-wave (32 lanes) per node, lane = 4 dims.
// ---------------------------------------------------------------------------
__global__ __launch_bounds__(256) void aggregate_k(
    const float* __restrict__ x, const int* __restrict__ offsets,
    const int* __restrict__ edge_src, float* __restrict__ xin) {
    const int node = blockIdx.x * 8 + (threadIdx.x >> 5);
    const int col = (threadIdx.x & 31) << 2;  // 0..124
    const int beg = offsets[node];
    const int end = offsets[node + 1];

    float4 a0 = make_float4(0.f, 0.f, 0.f, 0.f);
    float4 a1 = a0, a2 = a0, a3 = a0;
    int j = beg;
    for (; j + 3 < end; j += 4) {
        const int s0 = edge_src[j + 0];
        const int s1 = edge_src[j + 1];
        const int s2 = edge_src[j + 2];
        const int s3 = edge_src[j + 3];
        const float4 v0 = *reinterpret_cast<const float4*>(x + (size_t)s0 * DIN + col);
        const float4 v1 = *reinterpret_cast<const float4*>(x + (size_t)s1 * DIN + col);
        const float4 v2 = *reinterpret_cast<const float4*>(x + (size_t)s2 * DIN + col);
        const float4 v3 = *reinterpret_cast<const float4*>(x + (size_t)s3 * DIN + col);
        a0.x += v0.x; a0.y += v0.y; a0.z += v0.z; a0.w += v0.w;
        a1.x += v1.x; a1.y += v1.y; a1.z += v1.z; a1.w += v1.w;
        a2.x += v2.x; a2.y += v2.y; a2.z += v2.z; a2.w += v2.w;
        a3.x += v3.x; a3.y += v3.y; a3.z += v3.z; a3.w += v3.w;
    }
    for (; j < end; ++j) {
        const int s0 = edge_src[j];
        const float4 v0 = *reinterpret_cast<const float4*>(x + (size_t)s0 * DIN + col);
        a0.x += v0.x; a0.y += v0.y; a0.z += v0.z; a0.w += v0.w;
    }
    const float4 xv = *reinterpret_cast<const float4*>(x + (size_t)node * DIN + col);
    float4 r;
    r.x = xv.x + a0.x + a1.x + a2.x + a3.x;
    r.y = xv.y + a0.y + a1.y + a2.y + a3.y;
    r.z = xv.z + a0.z + a1.z + a2.z + a3.z;
    r.w = xv.w + a0.w + a1.w + a2.w + a3.w;
    *reinterpret_cast<float4*>(xin + (size_t)node * DIN + col) = r;
}

// ---------------------------------------------------------------------------
// GEMM structure (both layers):
//  block = 40 rows x 256 cols (250 blocks = 10000 rows exactly)
//  256 thr = 8 tm-groups x 32 tn; thread = 5 rows x 8 cols {4tn, 128+4tn}
//  K staged in BK=32 chunks: A-tile [40][32], W-tile [32][256] in LDS
// ---------------------------------------------------------------------------
#define BM 40
#define BK 32

// Kernel 2: h1 = xin @ W1 + b1 (+ BN1 partial sums)
__global__ __launch_bounds__(256) void gemm1_k(
    const float* __restrict__ xin, const float* __restrict__ W1,
    const float* __restrict__ b1, float* __restrict__ h1,
    float* __restrict__ sum1, float* __restrict__ sq1) {
    __shared__ float lds[BM * BK + BK * DOUT + 8 * DOUT];  // 46 KB
    float* xs = lds;                        // [40][32]
    float* ws = lds + BM * BK;              // [32][256]
    float* red = lds + BM * BK + BK * DOUT; // [8][256]
    const int tid = threadIdx.x;
    const int tm = tid >> 5, tn = tid & 31;
    const int row0 = blockIdx.x * BM;

    float4 accLo[5], accHi[5];
    const float4 bLo = reinterpret_cast<const float4*>(b1)[tn];
    const float4 bHi = reinterpret_cast<const float4*>(b1)[32 + tn];
#pragma unroll
    for (int r = 0; r < 5; ++r) { accLo[r] = bLo; accHi[r] = bHi; }

    for (int c = 0; c < DIN / BK; ++c) {
        __syncthreads();
        // stage A chunk: 40 rows x 32 cols = 320 float4
        for (int u = tid; u < BM * BK / 4; u += 256) {
            const int row = row0 + (u >> 3);
            const int c4 = u & 7;
            reinterpret_cast<float4*>(xs)[u] =
                reinterpret_cast<const float4*>(xin)[(size_t)row * (DIN / 4) + c * 8 + c4];
        }
        // stage W chunk: 32 rows x 256 cols = 2048 float4
        const float4* wsrc = reinterpret_cast<const float4*>(W1) + (size_t)c * BK * (DOUT / 4);
#pragma unroll
        for (int i = 0; i < 8; ++i)
            reinterpret_cast<float4*>(ws)[tid + 256 * i] = wsrc[tid + 256 * i];
        __syncthreads();

#pragma unroll
        for (int kk = 0; kk < 8; ++kk) {
            float4 av[5];
#pragma unroll
            for (int r = 0; r < 5; ++r)
                av[r] = reinterpret_cast<const float4*>(xs)[(5 * tm + r) * 8 + kk];
#pragma unroll
            for (int j = 0; j < 4; ++j) {
                const float4 wLo = reinterpret_cast<const float4*>(ws)[(kk * 4 + j) * 64 + tn];
                const float4 wHi = reinterpret_cast<const float4*>(ws)[(kk * 4 + j) * 64 + 32 + tn];
#pragma unroll
                for (int r = 0; r < 5; ++r) {
                    const float a = (j == 0) ? av[r].x : (j == 1) ? av[r].y
                                  : (j == 2) ? av[r].z : av[r].w;
                    accLo[r].x = fmaf(a, wLo.x, accLo[r].x);
                    accLo[r].y = fmaf(a, wLo.y, accLo[r].y);
                    accLo[r].z = fmaf(a, wLo.z, accLo[r].z);
                    accLo[r].w = fmaf(a, wLo.w, accLo[r].w);
                    accHi[r].x = fmaf(a, wHi.x, accHi[r].x);
                    accHi[r].y = fmaf(a, wHi.y, accHi[r].y);
                    accHi[r].z = fmaf(a, wHi.z, accHi[r].z);
                    accHi[r].w = fmaf(a, wHi.w, accHi[r].w);
                }
            }
        }
    }

    // store + per-thread column partials
    float4 sLo = make_float4(0.f, 0.f, 0.f, 0.f), sHi = sLo, qLo = sLo, qHi = sLo;
#pragma unroll
    for (int r = 0; r < 5; ++r) {
        const int row = row0 + 5 * tm + r;
        reinterpret_cast<float4*>(h1)[(size_t)row * 64 + tn] = accLo[r];
        reinterpret_cast<float4*>(h1)[(size_t)row * 64 + 32 + tn] = accHi[r];
        sLo.x += accLo[r].x; sLo.y += accLo[r].y; sLo.z += accLo[r].z; sLo.w += accLo[r].w;
        sHi.x += accHi[r].x; sHi.y += accHi[r].y; sHi.z += accHi[r].z; sHi.w += accHi[r].w;
        qLo.x += accLo[r].x * accLo[r].x; qLo.y += accLo[r].y * accLo[r].y;
        qLo.z += accLo[r].z * accLo[r].z; qLo.w += accLo[r].w * accLo[r].w;
        qHi.x += accHi[r].x * accHi[r].x; qHi.y += accHi[r].y * accHi[r].y;
        qHi.z += accHi[r].z * accHi[r].z; qHi.w += accHi[r].w * accHi[r].w;
    }
    __syncthreads();
    reinterpret_cast<float4*>(red)[tm * 64 + tn] = sLo;
    reinterpret_cast<float4*>(red)[tm * 64 + 32 + tn] = sHi;
    __syncthreads();
    {
        float s = 0.f;
#pragma unroll
        for (int g = 0; g < 8; ++g) s += red[g * 256 + tid];
        atomicAdd(&sum1[tid], s);
    }
    __syncthreads();
    reinterpret_cast<float4*>(red)[tm * 64 + tn] = qLo;
    reinterpret_cast<float4*>(red)[tm * 64 + 32 + tn] = qHi;
    __syncthreads();
    {
        float s = 0.f;
#pragma unroll
        for (int g = 0; g < 8; ++g) s += red[g * 256 + tid];
        atomicAdd(&sq1[tid], s);
    }
}

// ---------------------------------------------------------------------------
// Kernel 3: BN finalize -> per-feature scale/shift
// ---------------------------------------------------------------------------
__global__ void bn_final_k(const float* __restrict__ sum,
                           const float* __restrict__ sq,
                           const float* __restrict__ gamma,
                           const float* __restrict__ beta,
                           float* __restrict__ scale,
                           float* __restrict__ shift) {
    const int j = threadIdx.x;  // 256
    const float nInv = 1.0f / (float)NN;
    const float mean = sum[j] * nInv;
    const float var = sq[j] * nInv - mean * mean;
    const float sc = gamma[j] * rsqrtf(var + BN_EPS);
    scale[j] = sc;
    shift[j] = beta[j] - mean * sc;
}

// ---------------------------------------------------------------------------
// Kernel 4: h2 = relu(bn1(h1)) @ W2 + b2 (+ BN2 partial sums)
// ---------------------------------------------------------------------------
__global__ __launch_bounds__(256) void gemm2_k(
    const float* __restrict__ h1, const float* __restrict__ scale1,
    const float* __restrict__ shift1, const float* __restrict__ W2,
    const float* __restrict__ b2, float* __restrict__ h2,
    float* __restrict__ sum2, float* __restrict__ sq2) {
    __shared__ float lds[BM * BK + BK * DOUT + 8 * DOUT];
    float* xs = lds;
    float* ws = lds + BM * BK;
    float* red = lds + BM * BK + BK * DOUT;
    const int tid = threadIdx.x;
    const int tm = tid >> 5, tn = tid & 31;
    const int row0 = blockIdx.x * BM;

    float4 accLo[5], accHi[5];
    const float4 bLo = reinterpret_cast<const float4*>(b2)[tn];
    const float4 bHi = reinterpret_cast<const float4*>(b2)[32 + tn];
#pragma unroll
    for (int r = 0; r < 5; ++r) { accLo[r] = bLo; accHi[r] = bHi; }

    for (int c = 0; c < DOUT / BK; ++c) {
        __syncthreads();
        // stage A chunk with fused bn1+relu: 40 rows x 32 cols
        for (int u = tid; u < BM * BK / 4; u += 256) {
            const int row = row0 + (u >> 3);
            const int c4 = u & 7;
            const float4 h = reinterpret_cast<const float4*>(h1)[(size_t)row * 64 + c * 8 + c4];
            const float4 sc = reinterpret_cast<const float4*>(scale1)[c * 8 + c4];
            const float4 sh = reinterpret_cast<const float4*>(shift1)[c * 8 + c4];
            float4 g;
            g.x = fmaxf(fmaf(h.x, sc.x, sh.x), 0.f);
            g.y = fmaxf(fmaf(h.y, sc.y, sh.y), 0.f);
            g.z = fmaxf(fmaf(h.z, sc.z, sh.z), 0.f);
            g.w = fmaxf(fmaf(h.w, sc.w, sh.w), 0.f);
            reinterpret_cast<float4*>(xs)[u] = g;
        }
        const float4* wsrc = reinterpret_cast<const float4*>(W2) + (size_t)c * BK * (DOUT / 4);
#pragma unroll
        for (int i = 0; i < 8; ++i)
            reinterpret_cast<float4*>(ws)[tid + 256 * i] = wsrc[tid + 256 * i];
        __syncthreads();

#pragma unroll
        for (int kk = 0; kk < 8; ++kk) {
            float4 av[5];
#pragma unroll
            for (int r = 0; r < 5; ++r)
                av[r] = reinterpret_cast<const float4*>(xs)[(5 * tm + r) * 8 + kk];
#pragma unroll
            for (int j = 0; j < 4; ++j) {
                const float4 wLo = reinterpret_cast<const float4*>(ws)[(kk * 4 + j) * 64 + tn];
                const float4 wHi = reinterpret_cast<const float4*>(ws)[(kk * 4 + j) * 64 + 32 + tn];
#pragma unroll
                for (int r = 0; r < 5; ++r) {
                    const float a = (j == 0) ? av[r].x : (j == 1) ? av[r].y
                                  : (j == 2) ? av[r].z : av[r].w;
                    accLo[r].x = fmaf(a, wLo.x, accLo[r].x);
                    accLo[r].y = fmaf(a, wLo.y, accLo[r].y);
                    accLo[r].z = fmaf(a, wLo.z, accLo[r].z);
                    accLo[r].w = fmaf(a, wLo.w, accLo[r].w);
                    accHi[r].x = fmaf(a, wHi.x, accHi[r].x);
                    accHi[r].y = fmaf(a, wHi.y, accHi[r].y);
                    accHi[r].z = fmaf(a, wHi.z, accHi[r].z);
                    accHi[r].w = fmaf(a, wHi.w, accHi[r].w);
                }
            }
        }
    }

    float4 sLo = make_float4(0.f, 0.f, 0.f, 0.f), sHi = sLo, qLo = sLo, qHi = sLo;
#pragma unroll
    for (int r = 0; r < 5; ++r) {
        const int row = row0 + 5 * tm + r;
        reinterpret_cast<float4*>(h2)[(size_t)row * 64 + tn] = accLo[r];
        reinterpret_cast<float4*>(h2)[(size_t)row * 64 + 32 + tn] = accHi[r];
        sLo.x += accLo[r].x; sLo.y += accLo[r].y; sLo.z += accLo[r].z; sLo.w += accLo[r].w;
        sHi.x += accHi[r].x; sHi.y += accHi[r].y; sHi.z += accHi[r].z; sHi.w += accHi[r].w;
        qLo.x += accLo[r].x * accLo[r].x; qLo.y += accLo[r].y * accLo[r].y;
        qLo.z += accLo[r].z * accLo[r].z; qLo.w += accLo[r].w * accLo[r].w;
        qHi.x += accHi[r].x * accHi[r].x; qHi.y += accHi[r].y * accHi[r].y;
        qHi.z += accHi[r].z * accHi[r].z; qHi.w += accHi[r].w * accHi[r].w;
    }
    __syncthreads();
    reinterpret_cast<float4*>(red)[tm * 64 + tn] = sLo;
    reinterpret_cast<float4*>(red)[tm * 64 + 32 + tn] = sHi;
    __syncthreads();
    {
        float s = 0.f;
#pragma unroll
        for (int g = 0; g < 8; ++g) s += red[g * 256 + tid];
        atomicAdd(&sum2[tid], s);
    }
    __syncthreads();
    reinterpret_cast<float4*>(red)[tm * 64 + tn] = qLo;
    reinterpret_cast<float4*>(red)[tm * 64 + 32 + tn] = qHi;
    __syncthreads();
    {
        float s = 0.f;
#pragma unroll
        for (int g = 0; g < 8; ++g) s += red[g * 256 + tid];
        atomicAdd(&sq2[tid], s);
    }
}

// ---------------------------------------------------------------------------
// Kernel 5: out = relu(bn2(h2)), float4
// ---------------------------------------------------------------------------
__global__ __launch_bounds__(256) void bn_relu_out_k(
    const float* __restrict__ h2, const float* __restrict__ scale2,
    const float* __restrict__ shift2, float* __restrict__ out) {
    const int u = blockIdx.x * 256 + threadIdx.x;  // float4 index
    if (u < NN * DOUT / 4) {
        const int k4 = u & 63;
        const float4 h = reinterpret_cast<const float4*>(h2)[u];
        const float4 sc = reinterpret_cast<const float4*>(scale2)[k4];
        const float4 sh = reinterpret_cast<const float4*>(shift2)[k4];
        float4 g;
        g.x = fmaxf(fmaf(h.x, sc.x, sh.x), 0.f);
        g.y = fmaxf(fmaf(h.y, sc.y, sh.y), 0.f);
        g.z = fmaxf(fmaf(h.z, sc.z, sh.z), 0.f);
        g.w = fmaxf(fmaf(h.w, sc.w, sh.w), 0.f);
        reinterpret_cast<float4*>(out)[u] = g;
    }
}

// ---------------------------------------------------------------------------
extern "C" void kernel_launch(void* const* d_in, const int* in_sizes, int n_in,
                              void* d_out, int out_size, void* d_ws,
                              size_t ws_size, hipStream_t stream) {
    const float* x      = (const float*)d_in[0];
    const int*   ei     = (const int*)d_in[1];
    const float* W1     = (const float*)d_in[2];
    const float* b1     = (const float*)d_in[3];
    const float* gamma1 = (const float*)d_in[4];
    const float* beta1  = (const float*)d_in[5];
    const float* W2     = (const float*)d_in[6];
    const float* b2     = (const float*)d_in[7];
    const float* gamma2 = (const float*)d_in[8];
    const float* beta2  = (const float*)d_in[9];
    const int E = in_sizes[1] / 2;

    char* w = (char*)d_ws;
    float* stats   = (float*)w;
    float* sum1    = stats + 0;
    float* sq1     = stats + 256;
    float* scale1  = stats + 512;
    float* shift1  = stats + 768;
    float* sum2    = stats + 1024;
    float* sq2     = stats + 1280;
    float* scale2  = stats + 1536;
    float* shift2  = stats + 1792;
    int* deg       = (int*)(w + 8192);
    int* offsets   = (int*)(w + 8192 + 40064);
    int* cursor    = (int*)(w + 8192 + 2 * 40064);
    int* edge_src  = (int*)(w + 8192 + 3 * 40064);
    float* xin     = (float*)(w + 8192 + 3 * 40064 + (size_t)E * 4);
    float* h1      = xin + (size_t)NN * DIN;
    float* h2      = h1 + (size_t)NN * DOUT;
    float* out     = (float*)d_out;

    hipMemsetAsync(d_ws, 0, 8192 + 40064, stream);

    hist_k<<<80, 256, 0, stream>>>(ei, deg, E);
    scan_k<<<1, 1024, 0, stream>>>(deg, offsets, cursor);
    fill_k<<<2048, 256, 0, stream>>>(ei, cursor, edge_src, E);
    aggregate_k<<<NN / 8, 256, 0, stream>>>(x, offsets, edge_src, xin);
    gemm1_k<<<NN / BM, 256, 0, stream>>>(xin, W1, b1, h1, sum1, sq1);
    bn_final_k<<<1, 256, 0, stream>>>(sum1, sq1, gamma1, beta1, scale1, shift1);
    gemm2_k<<<NN / BM, 256, 0, stream>>>(h1, scale1, shift1, W2, b2, h2,
                                         sum2, sq2);
    bn_final_k<<<1, 256, 0, stream>>>(sum2, sq2, gamma2, beta2, scale2, shift2);
    bn_relu_out_k<<<NN * DOUT / 4 / 256, 256, 0, stream>>>(h2, scale2,
                                                           shift2, out);
}

// Round 6
// 146.522 us; speedup vs baseline: 1.7454x; 1.1066x over previous
//
#include <hip/hip_runtime.h>

#define NN 10000
#define DIN 128
#define DOUT 256
#define NB 64            // CSR-build blocks; E/NB edges each
static constexpr float BN_EPS = 1e-5f;

// ---------------------------------------------------------------------------
// Kernel H: per-block LDS histogram -> private slice hist_g[b][node] (no
// global atomics)
// ---------------------------------------------------------------------------
__global__ __launch_bounds__(256) void khist(const int* __restrict__ ei,
                                             int* __restrict__ hist_g, int E) {
    __shared__ int hist[NN];
    const int tid = threadIdx.x;
    for (int i = tid; i < NN; i += 256) hist[i] = 0;
    __syncthreads();
    const int chunk = (E + NB - 1) / NB;
    const int e0 = blockIdx.x * chunk;
    const int e1 = min(e0 + chunk, E);
    for (int e = e0 + tid; e < e1; e += 256) {
        atomicAdd(&hist[ei[E + e]], 1);
    }
    __syncthreads();
    int* dst = hist_g + (size_t)blockIdx.x * NN;
    for (int i = tid; i < NN; i += 256) dst[i] = hist[i];
}

// ---------------------------------------------------------------------------
// Kernel Sa: in-place exclusive scan of hist_g along block axis; total[node]
// grid = 40 x 256 = 10240 threads, one node each; per-b reads are coalesced.
// ---------------------------------------------------------------------------
__global__ __launch_bounds__(256) void kscan_a(int* __restrict__ hist_g,
                                               int* __restrict__ total) {
    const int node = blockIdx.x * 256 + threadIdx.x;
    if (node >= NN) return;
    int run = 0;
#pragma unroll 8
    for (int b = 0; b < NB; ++b) {
        const int v = hist_g[(size_t)b * NN + node];
        hist_g[(size_t)b * NN + node] = run;
        run += v;
    }
    total[node] = run;
}

// ---------------------------------------------------------------------------
// Kernel Sb: single-block exclusive scan (total[10000] -> offsets[10001])
// ---------------------------------------------------------------------------
__global__ __launch_bounds__(1024) void kscan_b(const int* __restrict__ total,
                                                int* __restrict__ offsets) {
    __shared__ int part[1024];
    const int t = threadIdx.x;
    const int base = t * 10;
    int local[10];
    int s = 0;
#pragma unroll
    for (int k = 0; k < 10; ++k) {
        const int i = base + k;
        const int v = (i < NN) ? total[i] : 0;
        local[k] = s;
        s += v;
    }
    part[t] = s;
    __syncthreads();
    for (int off = 1; off < 1024; off <<= 1) {
        int v = 0;
        if (t >= off) v = part[t - off];
        __syncthreads();
        if (t >= off) part[t] += v;
        __syncthreads();
    }
    const int prefix = (t == 0) ? 0 : part[t - 1];
#pragma unroll
    for (int k = 0; k < 10; ++k) {
        const int i = base + k;
        if (i < NN) offsets[i] = prefix + local[k];
    }
    if (t == 1023) offsets[NN] = part[1023];
}

// ---------------------------------------------------------------------------
// Kernel F: CSR fill, LDS cursor (offsets + per-block prefix), LDS atomics
// ---------------------------------------------------------------------------
__global__ __launch_bounds__(256) void kfill(const int* __restrict__ ei,
                                             const int* __restrict__ hist_g,
                                             const int* __restrict__ offsets,
                                             int* __restrict__ edge_src,
                                             int E) {
    __shared__ int cur[NN];
    const int tid = threadIdx.x;
    const int* base = hist_g + (size_t)blockIdx.x * NN;
    for (int i = tid; i < NN; i += 256) cur[i] = base[i] + offsets[i];
    __syncthreads();
    const int chunk = (E + NB - 1) / NB;
    const int e0 = blockIdx.x * chunk;
    const int e1 = min(e0 + chunk, E);
    for (int e = e0 + tid; e < e1; e += 256) {
        const int src = ei[e];
        const int dst = ei[E + e];
        const int pos = atomicAdd(&cur[dst], 1);
        edge_src[pos] = src;
    }
}

// ---------------------------------------------------------------------------
// Kernel A: gather-aggregate. Half-wave (32 lanes) per node, lane = 4 dims.
// ---------------------------------------------------------------------------
__global__ __launch_bounds__(256) void aggregate_k(
    const float* __restrict__ x, const int* __restrict__ offsets,
    const int* __restrict__ edge_src, float* __restrict__ xin) {
    const int node = blockIdx.x * 8 + (threadIdx.x >> 5);
    const int col = (threadIdx.x & 31) << 2;  // 0..124
    const int beg = offsets[node];
    const int end = offsets[node + 1];

    float4 a0 = make_float4(0.f, 0.f, 0.f, 0.f);
    float4 a1 = a0, a2 = a0, a3 = a0;
    int j = beg;
    for (; j + 3 < end; j += 4) {
        const int s0 = edge_src[j + 0];
        const int s1 = edge_src[j + 1];
        const int s2 = edge_src[j + 2];
        const int s3 = edge_src[j + 3];
        const float4 v0 = *reinterpret_cast<const float4*>(x + (size_t)s0 * DIN + col);
        const float4 v1 = *reinterpret_cast<const float4*>(x + (size_t)s1 * DIN + col);
        const float4 v2 = *reinterpret_cast<const float4*>(x + (size_t)s2 * DIN + col);
        const float4 v3 = *reinterpret_cast<const float4*>(x + (size_t)s3 * DIN + col);
        a0.x += v0.x; a0.y += v0.y; a0.z += v0.z; a0.w += v0.w;
        a1.x += v1.x; a1.y += v1.y; a1.z += v1.z; a1.w += v1.w;
        a2.x += v2.x; a2.y += v2.y; a2.z += v2.z; a2.w += v2.w;
        a3.x += v3.x; a3.y += v3.y; a3.z += v3.z; a3.w += v3.w;
    }
    for (; j < end; ++j) {
        const int s0 = edge_src[j];
        const float4 v0 = *reinterpret_cast<const float4*>(x + (size_t)s0 * DIN + col);
        a0.x += v0.x; a0.y += v0.y; a0.z += v0.z; a0.w += v0.w;
    }
    const float4 xv = *reinterpret_cast<const float4*>(x + (size_t)node * DIN + col);
    float4 r;
    r.x = xv.x + a0.x + a1.x + a2.x + a3.x;
    r.y = xv.y + a0.y + a1.y + a2.y + a3.y;
    r.z = xv.z + a0.z + a1.z + a2.z + a3.z;
    r.w = xv.w + a0.w + a1.w + a2.w + a3.w;
    *reinterpret_cast<float4*>(xin + (size_t)node * DIN + col) = r;
}

// ---------------------------------------------------------------------------
// GEMM structure (both layers):
//  block = 40 rows x 256 cols (250 blocks = 10000 rows exactly)
//  256 thr = 8 tm-groups x 32 tn; thread = 5 rows x 8 cols {4tn, 128+4tn}
//  K staged in BK=32 chunks: A-tile [40][32], W-tile [32][256] in LDS
// ---------------------------------------------------------------------------
#define BM 40
#define BK 32

// Kernel 2: h1 = xin @ W1 + b1 (+ BN1 partial sums)
__global__ __launch_bounds__(256) void gemm1_k(
    const float* __restrict__ xin, const float* __restrict__ W1,
    const float* __restrict__ b1, float* __restrict__ h1,
    float* __restrict__ sum1, float* __restrict__ sq1) {
    __shared__ float lds[BM * BK + BK * DOUT + 8 * DOUT];  // 46 KB
    float* xs = lds;                        // [40][32]
    float* ws = lds + BM * BK;              // [32][256]
    float* red = lds + BM * BK + BK * DOUT; // [8][256]
    const int tid = threadIdx.x;
    const int tm = tid >> 5, tn = tid & 31;
    const int row0 = blockIdx.x * BM;

    float4 accLo[5], accHi[5];
    const float4 bLo = reinterpret_cast<const float4*>(b1)[tn];
    const float4 bHi = reinterpret_cast<const float4*>(b1)[32 + tn];
#pragma unroll
    for (int r = 0; r < 5; ++r) { accLo[r] = bLo; accHi[r] = bHi; }

    for (int c = 0; c < DIN / BK; ++c) {
        __syncthreads();
        for (int u = tid; u < BM * BK / 4; u += 256) {
            const int row = row0 + (u >> 3);
            const int c4 = u & 7;
            reinterpret_cast<float4*>(xs)[u] =
                reinterpret_cast<const float4*>(xin)[(size_t)row * (DIN / 4) + c * 8 + c4];
        }
        const float4* wsrc = reinterpret_cast<const float4*>(W1) + (size_t)c * BK * (DOUT / 4);
#pragma unroll
        for (int i = 0; i < 8; ++i)
            reinterpret_cast<float4*>(ws)[tid + 256 * i] = wsrc[tid + 256 * i];
        __syncthreads();

#pragma unroll
        for (int kk = 0; kk < 8; ++kk) {
            float4 av[5];
#pragma unroll
            for (int r = 0; r < 5; ++r)
                av[r] = reinterpret_cast<const float4*>(xs)[(5 * tm + r) * 8 + kk];
#pragma unroll
            for (int j = 0; j < 4; ++j) {
                const float4 wLo = reinterpret_cast<const float4*>(ws)[(kk * 4 + j) * 64 + tn];
                const float4 wHi = reinterpret_cast<const float4*>(ws)[(kk * 4 + j) * 64 + 32 + tn];
#pragma unroll
                for (int r = 0; r < 5; ++r) {
                    const float a = (j == 0) ? av[r].x : (j == 1) ? av[r].y
                                  : (j == 2) ? av[r].z : av[r].w;
                    accLo[r].x = fmaf(a, wLo.x, accLo[r].x);
                    accLo[r].y = fmaf(a, wLo.y, accLo[r].y);
                    accLo[r].z = fmaf(a, wLo.z, accLo[r].z);
                    accLo[r].w = fmaf(a, wLo.w, accLo[r].w);
                    accHi[r].x = fmaf(a, wHi.x, accHi[r].x);
                    accHi[r].y = fmaf(a, wHi.y, accHi[r].y);
                    accHi[r].z = fmaf(a, wHi.z, accHi[r].z);
                    accHi[r].w = fmaf(a, wHi.w, accHi[r].w);
                }
            }
        }
    }

    float4 sLo = make_float4(0.f, 0.f, 0.f, 0.f), sHi = sLo, qLo = sLo, qHi = sLo;
#pragma unroll
    for (int r = 0; r < 5; ++r) {
        const int row = row0 + 5 * tm + r;
        reinterpret_cast<float4*>(h1)[(size_t)row * 64 + tn] = accLo[r];
        reinterpret_cast<float4*>(h1)[(size_t)row * 64 + 32 + tn] = accHi[r];
        sLo.x += accLo[r].x; sLo.y += accLo[r].y; sLo.z += accLo[r].z; sLo.w += accLo[r].w;
        sHi.x += accHi[r].x; sHi.y += accHi[r].y; sHi.z += accHi[r].z; sHi.w += accHi[r].w;
        qLo.x += accLo[r].x * accLo[r].x; qLo.y += accLo[r].y * accLo[r].y;
        qLo.z += accLo[r].z * accLo[r].z; qLo.w += accLo[r].w * accLo[r].w;
        qHi.x += accHi[r].x * accHi[r].x; qHi.y += accHi[r].y * accHi[r].y;
        qHi.z += accHi[r].z * accHi[r].z; qHi.w += accHi[r].w * accHi[r].w;
    }
    __syncthreads();
    reinterpret_cast<float4*>(red)[tm * 64 + tn] = sLo;
    reinterpret_cast<float4*>(red)[tm * 64 + 32 + tn] = sHi;
    __syncthreads();
    {
        float s = 0.f;
#pragma unroll
        for (int g = 0; g < 8; ++g) s += red[g * 256 + tid];
        atomicAdd(&sum1[tid], s);
    }
    __syncthreads();
    reinterpret_cast<float4*>(red)[tm * 64 + tn] = qLo;
    reinterpret_cast<float4*>(red)[tm * 64 + 32 + tn] = qHi;
    __syncthreads();
    {
        float s = 0.f;
#pragma unroll
        for (int g = 0; g < 8; ++g) s += red[g * 256 + tid];
        atomicAdd(&sq1[tid], s);
    }
}

// ---------------------------------------------------------------------------
// Kernel 3: BN finalize -> per-feature scale/shift
// ---------------------------------------------------------------------------
__global__ void bn_final_k(const float* __restrict__ sum,
                           const float* __restrict__ sq,
                           const float* __restrict__ gamma,
                           const float* __restrict__ beta,
                           float* __restrict__ scale,
                           float* __restrict__ shift) {
    const int j = threadIdx.x;  // 256
    const float nInv = 1.0f / (float)NN;
    const float mean = sum[j] * nInv;
    const float var = sq[j] * nInv - mean * mean;
    const float sc = gamma[j] * rsqrtf(var + BN_EPS);
    scale[j] = sc;
    shift[j] = beta[j] - mean * sc;
}

// ---------------------------------------------------------------------------
// Kernel 4: h2 = relu(bn1(h1)) @ W2 + b2 (+ BN2 partial sums)
// ---------------------------------------------------------------------------
__global__ __launch_bounds__(256) void gemm2_k(
    const float* __restrict__ h1, const float* __restrict__ scale1,
    const float* __restrict__ shift1, const float* __restrict__ W2,
    const float* __restrict__ b2, float* __restrict__ h2,
    float* __restrict__ sum2, float* __restrict__ sq2) {
    __shared__ float lds[BM * BK + BK * DOUT + 8 * DOUT];
    float* xs = lds;
    float* ws = lds + BM * BK;
    float* red = lds + BM * BK + BK * DOUT;
    const int tid = threadIdx.x;
    const int tm = tid >> 5, tn = tid & 31;
    const int row0 = blockIdx.x * BM;

    float4 accLo[5], accHi[5];
    const float4 bLo = reinterpret_cast<const float4*>(b2)[tn];
    const float4 bHi = reinterpret_cast<const float4*>(b2)[32 + tn];
#pragma unroll
    for (int r = 0; r < 5; ++r) { accLo[r] = bLo; accHi[r] = bHi; }

    for (int c = 0; c < DOUT / BK; ++c) {
        __syncthreads();
        for (int u = tid; u < BM * BK / 4; u += 256) {
            const int row = row0 + (u >> 3);
            const int c4 = u & 7;
            const float4 h = reinterpret_cast<const float4*>(h1)[(size_t)row * 64 + c * 8 + c4];
            const float4 sc = reinterpret_cast<const float4*>(scale1)[c * 8 + c4];
            const float4 sh = reinterpret_cast<const float4*>(shift1)[c * 8 + c4];
            float4 g;
            g.x = fmaxf(fmaf(h.x, sc.x, sh.x), 0.f);
            g.y = fmaxf(fmaf(h.y, sc.y, sh.y), 0.f);
            g.z = fmaxf(fmaf(h.z, sc.z, sh.z), 0.f);
            g.w = fmaxf(fmaf(h.w, sc.w, sh.w), 0.f);
            reinterpret_cast<float4*>(xs)[u] = g;
        }
        const float4* wsrc = reinterpret_cast<const float4*>(W2) + (size_t)c * BK * (DOUT / 4);
#pragma unroll
        for (int i = 0; i < 8; ++i)
            reinterpret_cast<float4*>(ws)[tid + 256 * i] = wsrc[tid + 256 * i];
        __syncthreads();

#pragma unroll
        for (int kk = 0; kk < 8; ++kk) {
            float4 av[5];
#pragma unroll
            for (int r = 0; r < 5; ++r)
                av[r] = reinterpret_cast<const float4*>(xs)[(5 * tm + r) * 8 + kk];
#pragma unroll
            for (int j = 0; j < 4; ++j) {
                const float4 wLo = reinterpret_cast<const float4*>(ws)[(kk * 4 + j) * 64 + tn];
                const float4 wHi = reinterpret_cast<const float4*>(ws)[(kk * 4 + j) * 64 + 32 + tn];
#pragma unroll
                for (int r = 0; r < 5; ++r) {
                    const float a = (j == 0) ? av[r].x : (j == 1) ? av[r].y
                                  : (j == 2) ? av[r].z : av[r].w;
                    accLo[r].x = fmaf(a, wLo.x, accLo[r].x);
                    accLo[r].y = fmaf(a, wLo.y, accLo[r].y);
                    accLo[r].z = fmaf(a, wLo.z, accLo[r].z);
                    accLo[r].w = fmaf(a, wLo.w, accLo[r].w);
                    accHi[r].x = fmaf(a, wHi.x, accHi[r].x);
                    accHi[r].y = fmaf(a, wHi.y, accHi[r].y);
                    accHi[r].z = fmaf(a, wHi.z, accHi[r].z);
                    accHi[r].w = fmaf(a, wHi.w, accHi[r].w);
                }
            }
        }
    }

    float4 sLo = make_float4(0.f, 0.f, 0.f, 0.f), sHi = sLo, qLo = sLo, qHi = sLo;
#pragma unroll
    for (int r = 0; r < 5; ++r) {
        const int row = row0 + 5 * tm + r;
        reinterpret_cast<float4*>(h2)[(size_t)row * 64 + tn] = accLo[r];
        reinterpret_cast<float4*>(h2)[(size_t)row * 64 + 32 + tn] = accHi[r];
        sLo.x += accLo[r].x; sLo.y += accLo[r].y; sLo.z += accLo[r].z; sLo.w += accLo[r].w;
        sHi.x += accHi[r].x; sHi.y += accHi[r].y; sHi.z += accHi[r].z; sHi.w += accHi[r].w;
        qLo.x += accLo[r].x * accLo[r].x; qLo.y += accLo[r].y * accLo[r].y;
        qLo.z += accLo[r].z * accLo[r].z; qLo.w += accLo[r].w * accLo[r].w;
        qHi.x += accHi[r].x * accHi[r].x; qHi.y += accHi[r].y * accHi[r].y;
        qHi.z += accHi[r].z * accHi[r].z; qHi.w += accHi[r].w * accHi[r].w;
    }
    __syncthreads();
    reinterpret_cast<float4*>(red)[tm * 64 + tn] = sLo;
    reinterpret_cast<float4*>(red)[tm * 64 + 32 + tn] = sHi;
    __syncthreads();
    {
        float s = 0.f;
#pragma unroll
        for (int g = 0; g < 8; ++g) s += red[g * 256 + tid];
        atomicAdd(&sum2[tid], s);
    }
    __syncthreads();
    reinterpret_cast<float4*>(red)[tm * 64 + tn] = qLo;
    reinterpret_cast<float4*>(red)[tm * 64 + 32 + tn] = qHi;
    __syncthreads();
    {
        float s = 0.f;
#pragma unroll
        for (int g = 0; g < 8; ++g) s += red[g * 256 + tid];
        atomicAdd(&sq2[tid], s);
    }
}

// ---------------------------------------------------------------------------
// Kernel 5: out = relu(bn2(h2)), float4
// ---------------------------------------------------------------------------
__global__ __launch_bounds__(256) void bn_relu_out_k(
    const float* __restrict__ h2, const float* __restrict__ scale2,
    const float* __restrict__ shift2, float* __restrict__ out) {
    const int u = blockIdx.x * 256 + threadIdx.x;  // float4 index
    if (u < NN * DOUT / 4) {
        const int k4 = u & 63;
        const float4 h = reinterpret_cast<const float4*>(h2)[u];
        const float4 sc = reinterpret_cast<const float4*>(scale2)[k4];
        const float4 sh = reinterpret_cast<const float4*>(shift2)[k4];
        float4 g;
        g.x = fmaxf(fmaf(h.x, sc.x, sh.x), 0.f);
        g.y = fmaxf(fmaf(h.y, sc.y, sh.y), 0.f);
        g.z = fmaxf(fmaf(h.z, sc.z, sh.z), 0.f);
        g.w = fmaxf(fmaf(h.w, sc.w, sh.w), 0.f);
        reinterpret_cast<float4*>(out)[u] = g;
    }
}

// ---------------------------------------------------------------------------
extern "C" void kernel_launch(void* const* d_in, const int* in_sizes, int n_in,
                              void* d_out, int out_size, void* d_ws,
                              size_t ws_size, hipStream_t stream) {
    const float* x      = (const float*)d_in[0];
    const int*   ei     = (const int*)d_in[1];
    const float* W1     = (const float*)d_in[2];
    const float* b1     = (const float*)d_in[3];
    const float* gamma1 = (const float*)d_in[4];
    const float* beta1  = (const float*)d_in[5];
    const float* W2     = (const float*)d_in[6];
    const float* b2     = (const float*)d_in[7];
    const float* gamma2 = (const float*)d_in[8];
    const float* beta2  = (const float*)d_in[9];
    const int E = in_sizes[1] / 2;

    // ws layout (bytes):
    // [stats 8192][hist_g NB*NN*4][offsets 40064][total 40064]
    // [edge_src 4E][xin N*DIN*4][h1 N*DOUT*4][h2 N*DOUT*4]
    char* w = (char*)d_ws;
    float* stats   = (float*)w;
    float* sum1    = stats + 0;
    float* sq1     = stats + 256;
    float* scale1  = stats + 512;
    float* shift1  = stats + 768;
    float* sum2    = stats + 1024;
    float* sq2     = stats + 1280;
    float* scale2  = stats + 1536;
    float* shift2  = stats + 1792;
    int* hist_g    = (int*)(w + 8192);
    int* offsets   = (int*)(w + 8192 + (size_t)NB * NN * 4);
    int* total     = (int*)(w + 8192 + (size_t)NB * NN * 4 + 40064);
    int* edge_src  = (int*)(w + 8192 + (size_t)NB * NN * 4 + 2 * 40064);
    float* xin     = (float*)(w + 8192 + (size_t)NB * NN * 4 + 2 * 40064 + (size_t)E * 4);
    float* h1      = xin + (size_t)NN * DIN;
    float* h2      = h1 + (size_t)NN * DOUT;
    float* out     = (float*)d_out;

    hipMemsetAsync(d_ws, 0, 8192, stream);  // stats only

    khist<<<NB, 256, 0, stream>>>(ei, hist_g, E);
    kscan_a<<<40, 256, 0, stream>>>(hist_g, total);
    kscan_b<<<1, 1024, 0, stream>>>(total, offsets);
    kfill<<<NB, 256, 0, stream>>>(ei, hist_g, offsets, edge_src, E);
    aggregate_k<<<NN / 8, 256, 0, stream>>>(x, offsets, edge_src, xin);
    gemm1_k<<<NN / BM, 256, 0, stream>>>(xin, W1, b1, h1, sum1, sq1);
    bn_final_k<<<1, 256, 0, stream>>>(sum1, sq1, gamma1, beta1, scale1, shift1);
    gemm2_k<<<NN / BM, 256, 0, stream>>>(h1, scale1, shift1, W2, b2, h2,
                                         sum2, sq2);
    bn_final_k<<<1, 256, 0, stream>>>(sum2, sq2, gamma2, beta2, scale2, shift2);
    bn_relu_out_k<<<NN * DOUT / 4 / 256, 256, 0, stream>>>(h2, scale2,
                                                           shift2, out);
}

// Round 7
// 132.459 us; speedup vs baseline: 1.9307x; 1.1062x over previous
//
#include <hip/hip_runtime.h>

#define NN 10000
#define DIN 128
#define DOUT 256
#define NB 64            // CSR-build blocks; E/NB edges each
static constexpr float BN_EPS = 1e-5f;

// ---------------------------------------------------------------------------
// Kernel H: per-block LDS histogram -> private slice hist_g[b][node]
// ---------------------------------------------------------------------------
__global__ __launch_bounds__(256) void khist(const int* __restrict__ ei,
                                             int* __restrict__ hist_g, int E) {
    __shared__ int hist[NN];
    const int tid = threadIdx.x;
    for (int i = tid; i < NN; i += 256) hist[i] = 0;
    __syncthreads();
    const int chunk = (E + NB - 1) / NB;
    const int e0 = blockIdx.x * chunk;
    const int e1 = min(e0 + chunk, E);
    for (int e = e0 + tid; e < e1; e += 256) {
        atomicAdd(&hist[ei[E + e]], 1);
    }
    __syncthreads();
    int* dst = hist_g + (size_t)blockIdx.x * NN;
    for (int i = tid; i < NN; i += 256) dst[i] = hist[i];
}

// ---------------------------------------------------------------------------
// Kernel Sa: in-place exclusive scan of hist_g along block axis; total[node]
// ---------------------------------------------------------------------------
__global__ __launch_bounds__(256) void kscan_a(int* __restrict__ hist_g,
                                               int* __restrict__ total) {
    const int node = blockIdx.x * 256 + threadIdx.x;
    if (node >= NN) return;
    int run = 0;
#pragma unroll 8
    for (int b = 0; b < NB; ++b) {
        const int v = hist_g[(size_t)b * NN + node];
        hist_g[(size_t)b * NN + node] = run;
        run += v;
    }
    total[node] = run;
}

// ---------------------------------------------------------------------------
// Kernel Sb: single-block exclusive scan (total -> offsets) + zero BN stats
// (replaces the hipMemsetAsync, which cost ~40 us as fillBufferAligned)
// ---------------------------------------------------------------------------
__global__ __launch_bounds__(1024) void kscan_b(const int* __restrict__ total,
                                                int* __restrict__ offsets,
                                                float* __restrict__ stats) {
    const int t = threadIdx.x;
    stats[t] = 0.f;            // 2048 floats: sums/sqs for BN1+BN2
    stats[t + 1024] = 0.f;
    __shared__ int part[1024];
    const int base = t * 10;
    int local[10];
    int s = 0;
#pragma unroll
    for (int k = 0; k < 10; ++k) {
        const int i = base + k;
        const int v = (i < NN) ? total[i] : 0;
        local[k] = s;
        s += v;
    }
    part[t] = s;
    __syncthreads();
    for (int off = 1; off < 1024; off <<= 1) {
        int v = 0;
        if (t >= off) v = part[t - off];
        __syncthreads();
        if (t >= off) part[t] += v;
        __syncthreads();
    }
    const int prefix = (t == 0) ? 0 : part[t - 1];
#pragma unroll
    for (int k = 0; k < 10; ++k) {
        const int i = base + k;
        if (i < NN) offsets[i] = prefix + local[k];
    }
    if (t == 1023) offsets[NN] = part[1023];
}

// ---------------------------------------------------------------------------
// Kernel F: CSR fill, LDS cursor (offsets + per-block prefix), LDS atomics
// ---------------------------------------------------------------------------
__global__ __launch_bounds__(256) void kfill(const int* __restrict__ ei,
                                             const int* __restrict__ hist_g,
                                             const int* __restrict__ offsets,
                                             int* __restrict__ edge_src,
                                             int E) {
    __shared__ int cur[NN];
    const int tid = threadIdx.x;
    const int* base = hist_g + (size_t)blockIdx.x * NN;
    for (int i = tid; i < NN; i += 256) cur[i] = base[i] + offsets[i];
    __syncthreads();
    const int chunk = (E + NB - 1) / NB;
    const int e0 = blockIdx.x * chunk;
    const int e1 = min(e0 + chunk, E);
    for (int e = e0 + tid; e < e1; e += 256) {
        const int src = ei[e];
        const int dst = ei[E + e];
        const int pos = atomicAdd(&cur[dst], 1);
        edge_src[pos] = src;
    }
}

// ---------------------------------------------------------------------------
// Kernel A: gather-aggregate. Half-wave (32 lanes) per node, lane = 4 dims.
// ---------------------------------------------------------------------------
__global__ __launch_bounds__(256) void aggregate_k(
    const float* __restrict__ x, const int* __restrict__ offsets,
    const int* __restrict__ edge_src, float* __restrict__ xin) {
    const int node = blockIdx.x * 8 + (threadIdx.x >> 5);
    const int col = (threadIdx.x & 31) << 2;  // 0..124
    const int beg = offsets[node];
    const int end = offsets[node + 1];

    float4 a0 = make_float4(0.f, 0.f, 0.f, 0.f);
    float4 a1 = a0, a2 = a0, a3 = a0;
    int j = beg;
    for (; j + 3 < end; j += 4) {
        const int s0 = edge_src[j + 0];
        const int s1 = edge_src[j + 1];
        const int s2 = edge_src[j + 2];
        const int s3 = edge_src[j + 3];
        const float4 v0 = *reinterpret_cast<const float4*>(x + (size_t)s0 * DIN + col);
        const float4 v1 = *reinterpret_cast<const float4*>(x + (size_t)s1 * DIN + col);
        const float4 v2 = *reinterpret_cast<const float4*>(x + (size_t)s2 * DIN + col);
        const float4 v3 = *reinterpret_cast<const float4*>(x + (size_t)s3 * DIN + col);
        a0.x += v0.x; a0.y += v0.y; a0.z += v0.z; a0.w += v0.w;
        a1.x += v1.x; a1.y += v1.y; a1.z += v1.z; a1.w += v1.w;
        a2.x += v2.x; a2.y += v2.y; a2.z += v2.z; a2.w += v2.w;
        a3.x += v3.x; a3.y += v3.y; a3.z += v3.z; a3.w += v3.w;
    }
    for (; j < end; ++j) {
        const int s0 = edge_src[j];
        const float4 v0 = *reinterpret_cast<const float4*>(x + (size_t)s0 * DIN + col);
        a0.x += v0.x; a0.y += v0.y; a0.z += v0.z; a0.w += v0.w;
    }
    const float4 xv = *reinterpret_cast<const float4*>(x + (size_t)node * DIN + col);
    float4 r;
    r.x = xv.x + a0.x + a1.x + a2.x + a3.x;
    r.y = xv.y + a0.y + a1.y + a2.y + a3.y;
    r.z = xv.z + a0.z + a1.z + a2.z + a3.z;
    r.w = xv.w + a0.w + a1.w + a2.w + a3.w;
    *reinterpret_cast<float4*>(xin + (size_t)node * DIN + col) = r;
}

// ---------------------------------------------------------------------------
// GEMM structure (both layers):
//  grid = 250 row-tiles x 2 col-halves = 500 blocks (2/CU for overlap)
//  block = 40 rows x 128 cols; 256 thr = 8 tm x 32 tn; thread = 5 rows x 4 cols
//  K staged in BK=32 chunks: A-tile [40][32], W-half [32][128] in LDS (~29KB)
// ---------------------------------------------------------------------------
#define BM 40
#define BK 32

// Kernel 2: h1 = xin @ W1 + b1 (+ BN1 partial sums)
__global__ __launch_bounds__(256) void gemm1_k(
    const float* __restrict__ xin, const float* __restrict__ W1,
    const float* __restrict__ b1, float* __restrict__ h1,
    float* __restrict__ sum1, float* __restrict__ sq1) {
    __shared__ float xs[BM * BK];        // 5 KB
    __shared__ float ws[BK * 128];       // 16 KB
    __shared__ float red_s[8 * 128];     // 4 KB
    __shared__ float red_q[8 * 128];     // 4 KB
    const int tid = threadIdx.x;
    const int tm = tid >> 5, tn = tid & 31;
    const int rt = blockIdx.x >> 1, nh = blockIdx.x & 1;
    const int row0 = rt * BM;

    float4 acc[5];
    const float4 bj = reinterpret_cast<const float4*>(b1)[nh * 32 + tn];
#pragma unroll
    for (int r = 0; r < 5; ++r) acc[r] = bj;

    for (int c = 0; c < DIN / BK; ++c) {
        __syncthreads();
        // stage A chunk: 40 rows x 8 float4 = 320 float4
        for (int u = tid; u < BM * BK / 4; u += 256) {
            const int row = row0 + (u >> 3);
            const int c4 = u & 7;
            reinterpret_cast<float4*>(xs)[u] =
                reinterpret_cast<const float4*>(xin)[(size_t)row * 32 + c * 8 + c4];
        }
        // stage W half-chunk: 32 k-rows x 32 float4 = 1024 float4
#pragma unroll
        for (int i = 0; i < 4; ++i) {
            const int u = tid + 256 * i;
            const int krow = u >> 5, cc = u & 31;
            reinterpret_cast<float4*>(ws)[u] =
                reinterpret_cast<const float4*>(W1)[(size_t)(c * BK + krow) * 64 + nh * 32 + cc];
        }
        __syncthreads();

#pragma unroll
        for (int kk = 0; kk < 8; ++kk) {
            float4 av[5];
#pragma unroll
            for (int r = 0; r < 5; ++r)
                av[r] = reinterpret_cast<const float4*>(xs)[(5 * tm + r) * 8 + kk];
#pragma unroll
            for (int j = 0; j < 4; ++j) {
                const float4 w = reinterpret_cast<const float4*>(ws)[(kk * 4 + j) * 32 + tn];
#pragma unroll
                for (int r = 0; r < 5; ++r) {
                    const float a = (j == 0) ? av[r].x : (j == 1) ? av[r].y
                                  : (j == 2) ? av[r].z : av[r].w;
                    acc[r].x = fmaf(a, w.x, acc[r].x);
                    acc[r].y = fmaf(a, w.y, acc[r].y);
                    acc[r].z = fmaf(a, w.z, acc[r].z);
                    acc[r].w = fmaf(a, w.w, acc[r].w);
                }
            }
        }
    }

    // store + per-thread column partials
    float4 s4 = make_float4(0.f, 0.f, 0.f, 0.f), q4 = s4;
#pragma unroll
    for (int r = 0; r < 5; ++r) {
        const int row = row0 + 5 * tm + r;
        reinterpret_cast<float4*>(h1)[(size_t)row * 64 + nh * 32 + tn] = acc[r];
        s4.x += acc[r].x; s4.y += acc[r].y; s4.z += acc[r].z; s4.w += acc[r].w;
        q4.x += acc[r].x * acc[r].x; q4.y += acc[r].y * acc[r].y;
        q4.z += acc[r].z * acc[r].z; q4.w += acc[r].w * acc[r].w;
    }
    __syncthreads();
    reinterpret_cast<float4*>(red_s)[tm * 32 + tn] = s4;
    reinterpret_cast<float4*>(red_q)[tm * 32 + tn] = q4;
    __syncthreads();
    if (tid < 128) {
        float s = 0.f;
#pragma unroll
        for (int g = 0; g < 8; ++g) s += red_s[g * 128 + tid];
        atomicAdd(&sum1[nh * 128 + tid], s);
    } else {
        const int col = tid - 128;
        float q = 0.f;
#pragma unroll
        for (int g = 0; g < 8; ++g) q += red_q[g * 128 + col];
        atomicAdd(&sq1[nh * 128 + col], q);
    }
}

// ---------------------------------------------------------------------------
// Kernel 3: BN finalize -> per-feature scale/shift
// ---------------------------------------------------------------------------
__global__ void bn_final_k(const float* __restrict__ sum,
                           const float* __restrict__ sq,
                           const float* __restrict__ gamma,
                           const float* __restrict__ beta,
                           float* __restrict__ scale,
                           float* __restrict__ shift) {
    const int j = threadIdx.x;  // 256
    const float nInv = 1.0f / (float)NN;
    const float mean = sum[j] * nInv;
    const float var = sq[j] * nInv - mean * mean;
    const float sc = gamma[j] * rsqrtf(var + BN_EPS);
    scale[j] = sc;
    shift[j] = beta[j] - mean * sc;
}

// ---------------------------------------------------------------------------
// Kernel 4: h2 = relu(bn1(h1)) @ W2 + b2 (+ BN2 partial sums)
// ---------------------------------------------------------------------------
__global__ __launch_bounds__(256) void gemm2_k(
    const float* __restrict__ h1, const float* __restrict__ scale1,
    const float* __restrict__ shift1, const float* __restrict__ W2,
    const float* __restrict__ b2, float* __restrict__ h2,
    float* __restrict__ sum2, float* __restrict__ sq2) {
    __shared__ float xs[BM * BK];
    __shared__ float ws[BK * 128];
    __shared__ float red_s[8 * 128];
    __shared__ float red_q[8 * 128];
    const int tid = threadIdx.x;
    const int tm = tid >> 5, tn = tid & 31;
    const int rt = blockIdx.x >> 1, nh = blockIdx.x & 1;
    const int row0 = rt * BM;

    float4 acc[5];
    const float4 bj = reinterpret_cast<const float4*>(b2)[nh * 32 + tn];
#pragma unroll
    for (int r = 0; r < 5; ++r) acc[r] = bj;

    for (int c = 0; c < DOUT / BK; ++c) {
        __syncthreads();
        // stage A chunk with fused bn1+relu: 40 rows x 8 float4
        for (int u = tid; u < BM * BK / 4; u += 256) {
            const int row = row0 + (u >> 3);
            const int c4 = u & 7;
            const float4 h = reinterpret_cast<const float4*>(h1)[(size_t)row * 64 + c * 8 + c4];
            const float4 sc = reinterpret_cast<const float4*>(scale1)[c * 8 + c4];
            const float4 sh = reinterpret_cast<const float4*>(shift1)[c * 8 + c4];
            float4 g;
            g.x = fmaxf(fmaf(h.x, sc.x, sh.x), 0.f);
            g.y = fmaxf(fmaf(h.y, sc.y, sh.y), 0.f);
            g.z = fmaxf(fmaf(h.z, sc.z, sh.z), 0.f);
            g.w = fmaxf(fmaf(h.w, sc.w, sh.w), 0.f);
            reinterpret_cast<float4*>(xs)[u] = g;
        }
        // stage W half-chunk
#pragma unroll
        for (int i = 0; i < 4; ++i) {
            const int u = tid + 256 * i;
            const int krow = u >> 5, cc = u & 31;
            reinterpret_cast<float4*>(ws)[u] =
                reinterpret_cast<const float4*>(W2)[(size_t)(c * BK + krow) * 64 + nh * 32 + cc];
        }
        __syncthreads();

#pragma unroll
        for (int kk = 0; kk < 8; ++kk) {
            float4 av[5];
#pragma unroll
            for (int r = 0; r < 5; ++r)
                av[r] = reinterpret_cast<const float4*>(xs)[(5 * tm + r) * 8 + kk];
#pragma unroll
            for (int j = 0; j < 4; ++j) {
                const float4 w = reinterpret_cast<const float4*>(ws)[(kk * 4 + j) * 32 + tn];
#pragma unroll
                for (int r = 0; r < 5; ++r) {
                    const float a = (j == 0) ? av[r].x : (j == 1) ? av[r].y
                                  : (j == 2) ? av[r].z : av[r].w;
                    acc[r].x = fmaf(a, w.x, acc[r].x);
                    acc[r].y = fmaf(a, w.y, acc[r].y);
                    acc[r].z = fmaf(a, w.z, acc[r].z);
                    acc[r].w = fmaf(a, w.w, acc[r].w);
                }
            }
        }
    }

    float4 s4 = make_float4(0.f, 0.f, 0.f, 0.f), q4 = s4;
#pragma unroll
    for (int r = 0; r < 5; ++r) {
        const int row = row0 + 5 * tm + r;
        reinterpret_cast<float4*>(h2)[(size_t)row * 64 + nh * 32 + tn] = acc[r];
        s4.x += acc[r].x; s4.y += acc[r].y; s4.z += acc[r].z; s4.w += acc[r].w;
        q4.x += acc[r].x * acc[r].x; q4.y += acc[r].y * acc[r].y;
        q4.z += acc[r].z * acc[r].z; q4.w += acc[r].w * acc[r].w;
    }
    __syncthreads();
    reinterpret_cast<float4*>(red_s)[tm * 32 + tn] = s4;
    reinterpret_cast<float4*>(red_q)[tm * 32 + tn] = q4;
    __syncthreads();
    if (tid < 128) {
        float s = 0.f;
#pragma unroll
        for (int g = 0; g < 8; ++g) s += red_s[g * 128 + tid];
        atomicAdd(&sum2[nh * 128 + tid], s);
    } else {
        const int col = tid - 128;
        float q = 0.f;
#pragma unroll
        for (int g = 0; g < 8; ++g) q += red_q[g * 128 + col];
        atomicAdd(&sq2[nh * 128 + col], q);
    }
}

// ---------------------------------------------------------------------------
// Kernel 5: out = relu(bn2(h2)), float4
// ---------------------------------------------------------------------------
__global__ __launch_bounds__(256) void bn_relu_out_k(
    const float* __restrict__ h2, const float* __restrict__ scale2,
    const float* __restrict__ shift2, float* __restrict__ out) {
    const int u = blockIdx.x * 256 + threadIdx.x;  // float4 index
    if (u < NN * DOUT / 4) {
        const int k4 = u & 63;
        const float4 h = reinterpret_cast<const float4*>(h2)[u];
        const float4 sc = reinterpret_cast<const float4*>(scale2)[k4];
        const float4 sh = reinterpret_cast<const float4*>(shift2)[k4];
        float4 g;
        g.x = fmaxf(fmaf(h.x, sc.x, sh.x), 0.f);
        g.y = fmaxf(fmaf(h.y, sc.y, sh.y), 0.f);
        g.z = fmaxf(fmaf(h.z, sc.z, sh.z), 0.f);
        g.w = fmaxf(fmaf(h.w, sc.w, sh.w), 0.f);
        reinterpret_cast<float4*>(out)[u] = g;
    }
}

// ---------------------------------------------------------------------------
extern "C" void kernel_launch(void* const* d_in, const int* in_sizes, int n_in,
                              void* d_out, int out_size, void* d_ws,
                              size_t ws_size, hipStream_t stream) {
    const float* x      = (const float*)d_in[0];
    const int*   ei     = (const int*)d_in[1];
    const float* W1     = (const float*)d_in[2];
    const float* b1     = (const float*)d_in[3];
    const float* gamma1 = (const float*)d_in[4];
    const float* beta1  = (const float*)d_in[5];
    const float* W2     = (const float*)d_in[6];
    const float* b2     = (const float*)d_in[7];
    const float* gamma2 = (const float*)d_in[8];
    const float* beta2  = (const float*)d_in[9];
    const int E = in_sizes[1] / 2;

    // ws layout (bytes):
    // [stats 8192][hist_g NB*NN*4][offsets 40064][total 40064]
    // [edge_src 4E][xin N*DIN*4][h1 N*DOUT*4][h2 N*DOUT*4]
    char* w = (char*)d_ws;
    float* stats   = (float*)w;
    float* sum1    = stats + 0;
    float* sq1     = stats + 256;
    float* scale1  = stats + 512;
    float* shift1  = stats + 768;
    float* sum2    = stats + 1024;
    float* sq2     = stats + 1280;
    float* scale2  = stats + 1536;
    float* shift2  = stats + 1792;
    int* hist_g    = (int*)(w + 8192);
    int* offsets   = (int*)(w + 8192 + (size_t)NB * NN * 4);
    int* total     = (int*)(w + 8192 + (size_t)NB * NN * 4 + 40064);
    int* edge_src  = (int*)(w + 8192 + (size_t)NB * NN * 4 + 2 * 40064);
    float* xin     = (float*)(w + 8192 + (size_t)NB * NN * 4 + 2 * 40064 + (size_t)E * 4);
    float* h1      = xin + (size_t)NN * DIN;
    float* h2      = h1 + (size_t)NN * DOUT;
    float* out     = (float*)d_out;

    khist<<<NB, 256, 0, stream>>>(ei, hist_g, E);
    kscan_a<<<40, 256, 0, stream>>>(hist_g, total);
    kscan_b<<<1, 1024, 0, stream>>>(total, offsets, stats);
    kfill<<<NB, 256, 0, stream>>>(ei, hist_g, offsets, edge_src, E);
    aggregate_k<<<NN / 8, 256, 0, stream>>>(x, offsets, edge_src, xin);
    gemm1_k<<<2 * NN / BM, 256, 0, stream>>>(xin, W1, b1, h1, sum1, sq1);
    bn_final_k<<<1, 256, 0, stream>>>(sum1, sq1, gamma1, beta1, scale1, shift1);
    gemm2_k<<<2 * NN / BM, 256, 0, stream>>>(h1, scale1, shift1, W2, b2, h2,
                                             sum2, sq2);
    bn_final_k<<<1, 256, 0, stream>>>(sum2, sq2, gamma2, beta2, scale2, shift2);
    bn_relu_out_k<<<NN * DOUT / 4 / 256, 256, 0, stream>>>(h2, scale2,
                                                           shift2, out);
}

// Round 8
// 128.261 us; speedup vs baseline: 1.9939x; 1.0327x over previous
//
#include <hip/hip_runtime.h>

#define NN 10000
#define DIN 128
#define DOUT 256
#define NB 64            // CSR-build blocks; E/NB edges each
static constexpr float BN_EPS = 1e-5f;

__device__ __forceinline__ unsigned short bf16r(float f) {
    unsigned int u = __float_as_uint(f);
    u += 0x7FFFu + ((u >> 16) & 1u);   // round-to-nearest-even
    return (unsigned short)(u >> 16);
}
__device__ __forceinline__ float bf16f(unsigned short h) {
    return __uint_as_float((unsigned int)h << 16);
}

// ---------------------------------------------------------------------------
// Kernel X: x (fp32) -> xb (bf16)
// ---------------------------------------------------------------------------
__global__ __launch_bounds__(256) void xcast_k(const float* __restrict__ x,
                                               ushort* __restrict__ xb) {
    const int u = blockIdx.x * 256 + threadIdx.x;  // float4 index
    if (u < NN * DIN / 4) {
        const float4 v = reinterpret_cast<const float4*>(x)[u];
        ushort4 o;
        o.x = bf16r(v.x); o.y = bf16r(v.y); o.z = bf16r(v.z); o.w = bf16r(v.w);
        reinterpret_cast<ushort4*>(xb)[u] = o;
    }
}

// ---------------------------------------------------------------------------
// Kernel H: per-block LDS histogram -> private slice hist_g[b][node]
// ---------------------------------------------------------------------------
__global__ __launch_bounds__(256) void khist(const int* __restrict__ ei,
                                             int* __restrict__ hist_g, int E) {
    __shared__ int hist[NN];
    const int tid = threadIdx.x;
    for (int i = tid; i < NN; i += 256) hist[i] = 0;
    __syncthreads();
    const int chunk = (E + NB - 1) / NB;
    const int e0 = blockIdx.x * chunk;
    const int e1 = min(e0 + chunk, E);
    for (int e = e0 + tid; e < e1; e += 256) {
        atomicAdd(&hist[ei[E + e]], 1);
    }
    __syncthreads();
    int* dst = hist_g + (size_t)blockIdx.x * NN;
    for (int i = tid; i < NN; i += 256) dst[i] = hist[i];
}

// ---------------------------------------------------------------------------
// Kernel Sa: in-place exclusive scan of hist_g along block axis; total[node]
// ---------------------------------------------------------------------------
__global__ __launch_bounds__(256) void kscan_a(int* __restrict__ hist_g,
                                               int* __restrict__ total) {
    const int node = blockIdx.x * 256 + threadIdx.x;
    if (node >= NN) return;
    int run = 0;
#pragma unroll 8
    for (int b = 0; b < NB; ++b) {
        const int v = hist_g[(size_t)b * NN + node];
        hist_g[(size_t)b * NN + node] = run;
        run += v;
    }
    total[node] = run;
}

// ---------------------------------------------------------------------------
// Kernel Sb: single-block exclusive scan (total -> offsets) + zero BN stats
// ---------------------------------------------------------------------------
__global__ __launch_bounds__(1024) void kscan_b(const int* __restrict__ total,
                                                int* __restrict__ offsets,
                                                float* __restrict__ stats) {
    const int t = threadIdx.x;
    stats[t] = 0.f;            // 2048 floats: sums/sqs for BN1+BN2
    stats[t + 1024] = 0.f;
    __shared__ int part[1024];
    const int base = t * 10;
    int local[10];
    int s = 0;
#pragma unroll
    for (int k = 0; k < 10; ++k) {
        const int i = base + k;
        const int v = (i < NN) ? total[i] : 0;
        local[k] = s;
        s += v;
    }
    part[t] = s;
    __syncthreads();
    for (int off = 1; off < 1024; off <<= 1) {
        int v = 0;
        if (t >= off) v = part[t - off];
        __syncthreads();
        if (t >= off) part[t] += v;
        __syncthreads();
    }
    const int prefix = (t == 0) ? 0 : part[t - 1];
#pragma unroll
    for (int k = 0; k < 10; ++k) {
        const int i = base + k;
        if (i < NN) offsets[i] = prefix + local[k];
    }
    if (t == 1023) offsets[NN] = part[1023];
}

// ---------------------------------------------------------------------------
// Kernel F: CSR fill, LDS cursor (offsets + per-block prefix), LDS atomics
// ---------------------------------------------------------------------------
__global__ __launch_bounds__(256) void kfill(const int* __restrict__ ei,
                                             const int* __restrict__ hist_g,
                                             const int* __restrict__ offsets,
                                             int* __restrict__ edge_src,
                                             int E) {
    __shared__ int cur[NN];
    const int tid = threadIdx.x;
    const int* base = hist_g + (size_t)blockIdx.x * NN;
    for (int i = tid; i < NN; i += 256) cur[i] = base[i] + offsets[i];
    __syncthreads();
    const int chunk = (E + NB - 1) / NB;
    const int e0 = blockIdx.x * chunk;
    const int e1 = min(e0 + chunk, E);
    for (int e = e0 + tid; e < e1; e += 256) {
        const int src = ei[e];
        const int dst = ei[E + e];
        const int pos = atomicAdd(&cur[dst], 1);
        edge_src[pos] = src;
    }
}

// ---------------------------------------------------------------------------
// Kernel A: gather-aggregate in bf16. Half-wave per node; lane = 4 dims
// (ushort4 = 8 B). 8-deep unroll. Self term from fp32 x. Output bf16 xin.
// ---------------------------------------------------------------------------
__global__ __launch_bounds__(256) void aggregate_k(
    const float* __restrict__ x, const ushort* __restrict__ xb,
    const int* __restrict__ offsets, const int* __restrict__ edge_src,
    ushort* __restrict__ xin) {
    const int node = blockIdx.x * 8 + (threadIdx.x >> 5);
    const int c4 = threadIdx.x & 31;  // ushort4 index in row (32*4=128 dims)
    const int beg = offsets[node];
    const int end = offsets[node + 1];
    const ushort4* xb4 = reinterpret_cast<const ushort4*>(xb);

    float4 a0 = make_float4(0.f, 0.f, 0.f, 0.f);
    float4 a1 = a0, a2 = a0, a3 = a0;
    int j = beg;
    for (; j + 7 < end; j += 8) {
        int s[8];
#pragma unroll
        for (int t = 0; t < 8; ++t) s[t] = edge_src[j + t];
        ushort4 v[8];
#pragma unroll
        for (int t = 0; t < 8; ++t) v[t] = xb4[(size_t)s[t] * 32 + c4];
#pragma unroll
        for (int t = 0; t < 8; ++t) {
            float4* a = (t & 3) == 0 ? &a0 : (t & 3) == 1 ? &a1
                      : (t & 3) == 2 ? &a2 : &a3;
            a->x += bf16f(v[t].x);
            a->y += bf16f(v[t].y);
            a->z += bf16f(v[t].z);
            a->w += bf16f(v[t].w);
        }
    }
    for (; j < end; ++j) {
        const ushort4 v = xb4[(size_t)edge_src[j] * 32 + c4];
        a0.x += bf16f(v.x); a0.y += bf16f(v.y);
        a0.z += bf16f(v.z); a0.w += bf16f(v.w);
    }
    const float4 xv =
        reinterpret_cast<const float4*>(x)[(size_t)node * 32 + c4];
    float4 r;
    r.x = xv.x + a0.x + a1.x + a2.x + a3.x;
    r.y = xv.y + a0.y + a1.y + a2.y + a3.y;
    r.z = xv.z + a0.z + a1.z + a2.z + a3.z;
    r.w = xv.w + a0.w + a1.w + a2.w + a3.w;
    ushort4 o;
    o.x = bf16r(r.x); o.y = bf16r(r.y); o.z = bf16r(r.z); o.w = bf16r(r.w);
    reinterpret_cast<ushort4*>(xin)[(size_t)node * 32 + c4] = o;
}

// ---------------------------------------------------------------------------
// GEMM structure (both layers):
//  grid = 250 row-tiles x 2 col-halves = 500 blocks
//  block = 40 rows x 128 cols; 256 thr = 8 tm x 32 tn; thread = 5 rows x 4 cols
//  K staged in BK=32 chunks: A-tile [40][32] fp32 (converted), W-half [32][128]
// ---------------------------------------------------------------------------
#define BM 40
#define BK 32

// Kernel 2: h1 = xin @ W1 + b1 (+ BN1 partial sums); xin is bf16
__global__ __launch_bounds__(256) void gemm1_k(
    const ushort* __restrict__ xin, const float* __restrict__ W1,
    const float* __restrict__ b1, float* __restrict__ h1,
    float* __restrict__ sum1, float* __restrict__ sq1) {
    __shared__ float xs[BM * BK];        // 5 KB
    __shared__ float ws[BK * 128];       // 16 KB
    __shared__ float red_s[8 * 128];     // 4 KB
    __shared__ float red_q[8 * 128];     // 4 KB
    const int tid = threadIdx.x;
    const int tm = tid >> 5, tn = tid & 31;
    const int rt = blockIdx.x >> 1, nh = blockIdx.x & 1;
    const int row0 = rt * BM;

    float4 acc[5];
    const float4 bj = reinterpret_cast<const float4*>(b1)[nh * 32 + tn];
#pragma unroll
    for (int r = 0; r < 5; ++r) acc[r] = bj;

    for (int c = 0; c < DIN / BK; ++c) {
        __syncthreads();
        // stage A chunk (bf16 -> fp32): 40 rows x 8 ushort4 = 320
        for (int u = tid; u < BM * BK / 4; u += 256) {
            const int row = row0 + (u >> 3);
            const int cc = u & 7;
            const ushort4 v =
                reinterpret_cast<const ushort4*>(xin)[(size_t)row * 32 + c * 8 + cc];
            float4 f;
            f.x = bf16f(v.x); f.y = bf16f(v.y);
            f.z = bf16f(v.z); f.w = bf16f(v.w);
            reinterpret_cast<float4*>(xs)[u] = f;
        }
        // stage W half-chunk: 32 k-rows x 32 float4 = 1024 float4
#pragma unroll
        for (int i = 0; i < 4; ++i) {
            const int u = tid + 256 * i;
            const int krow = u >> 5, cc = u & 31;
            reinterpret_cast<float4*>(ws)[u] =
                reinterpret_cast<const float4*>(W1)[(size_t)(c * BK + krow) * 64 + nh * 32 + cc];
        }
        __syncthreads();

#pragma unroll
        for (int kk = 0; kk < 8; ++kk) {
            float4 av[5];
#pragma unroll
            for (int r = 0; r < 5; ++r)
                av[r] = reinterpret_cast<const float4*>(xs)[(5 * tm + r) * 8 + kk];
#pragma unroll
            for (int j = 0; j < 4; ++j) {
                const float4 w = reinterpret_cast<const float4*>(ws)[(kk * 4 + j) * 32 + tn];
#pragma unroll
                for (int r = 0; r < 5; ++r) {
                    const float a = (j == 0) ? av[r].x : (j == 1) ? av[r].y
                                  : (j == 2) ? av[r].z : av[r].w;
                    acc[r].x = fmaf(a, w.x, acc[r].x);
                    acc[r].y = fmaf(a, w.y, acc[r].y);
                    acc[r].z = fmaf(a, w.z, acc[r].z);
                    acc[r].w = fmaf(a, w.w, acc[r].w);
                }
            }
        }
    }

    float4 s4 = make_float4(0.f, 0.f, 0.f, 0.f), q4 = s4;
#pragma unroll
    for (int r = 0; r < 5; ++r) {
        const int row = row0 + 5 * tm + r;
        reinterpret_cast<float4*>(h1)[(size_t)row * 64 + nh * 32 + tn] = acc[r];
        s4.x += acc[r].x; s4.y += acc[r].y; s4.z += acc[r].z; s4.w += acc[r].w;
        q4.x += acc[r].x * acc[r].x; q4.y += acc[r].y * acc[r].y;
        q4.z += acc[r].z * acc[r].z; q4.w += acc[r].w * acc[r].w;
    }
    __syncthreads();
    reinterpret_cast<float4*>(red_s)[tm * 32 + tn] = s4;
    reinterpret_cast<float4*>(red_q)[tm * 32 + tn] = q4;
    __syncthreads();
    if (tid < 128) {
        float s = 0.f;
#pragma unroll
        for (int g = 0; g < 8; ++g) s += red_s[g * 128 + tid];
        atomicAdd(&sum1[nh * 128 + tid], s);
    } else {
        const int col = tid - 128;
        float q = 0.f;
#pragma unroll
        for (int g = 0; g < 8; ++g) q += red_q[g * 128 + col];
        atomicAdd(&sq1[nh * 128 + col], q);
    }
}

// ---------------------------------------------------------------------------
// Kernel 4: h2 = relu(bn1(h1)) @ W2 + b2 (+ BN2 partial sums)
// BN1 finalize fused into prologue (computes scale/shift from sums in LDS)
// ---------------------------------------------------------------------------
__global__ __launch_bounds__(256) void gemm2_k(
    const float* __restrict__ h1, const float* __restrict__ sum1,
    const float* __restrict__ sq1, const float* __restrict__ gamma1,
    const float* __restrict__ beta1, const float* __restrict__ W2,
    const float* __restrict__ b2, float* __restrict__ h2,
    float* __restrict__ sum2, float* __restrict__ sq2) {
    __shared__ float xs[BM * BK];
    __shared__ float ws[BK * 128];
    __shared__ float red_s[8 * 128];
    __shared__ float red_q[8 * 128];
    __shared__ float sc1[DOUT];
    __shared__ float sh1[DOUT];
    const int tid = threadIdx.x;
    const int tm = tid >> 5, tn = tid & 31;
    const int rt = blockIdx.x >> 1, nh = blockIdx.x & 1;
    const int row0 = rt * BM;

    {   // fused BN1 finalize (all 256 features; needed for K staging)
        const float nInv = 1.0f / (float)NN;
        const float mean = sum1[tid] * nInv;
        const float var = sq1[tid] * nInv - mean * mean;
        const float s = gamma1[tid] * rsqrtf(var + BN_EPS);
        sc1[tid] = s;
        sh1[tid] = beta1[tid] - mean * s;
    }

    float4 acc[5];
    const float4 bj = reinterpret_cast<const float4*>(b2)[nh * 32 + tn];
#pragma unroll
    for (int r = 0; r < 5; ++r) acc[r] = bj;

    for (int c = 0; c < DOUT / BK; ++c) {
        __syncthreads();
        // stage A chunk with fused bn1+relu: 40 rows x 8 float4
        for (int u = tid; u < BM * BK / 4; u += 256) {
            const int row = row0 + (u >> 3);
            const int cc = u & 7;
            const float4 h = reinterpret_cast<const float4*>(h1)[(size_t)row * 64 + c * 8 + cc];
            const float4 sc = reinterpret_cast<const float4*>(sc1)[c * 8 + cc];
            const float4 sh = reinterpret_cast<const float4*>(sh1)[c * 8 + cc];
            float4 g;
            g.x = fmaxf(fmaf(h.x, sc.x, sh.x), 0.f);
            g.y = fmaxf(fmaf(h.y, sc.y, sh.y), 0.f);
            g.z = fmaxf(fmaf(h.z, sc.z, sh.z), 0.f);
            g.w = fmaxf(fmaf(h.w, sc.w, sh.w), 0.f);
            reinterpret_cast<float4*>(xs)[u] = g;
        }
        // stage W half-chunk
#pragma unroll
        for (int i = 0; i < 4; ++i) {
            const int u = tid + 256 * i;
            const int krow = u >> 5, cc = u & 31;
            reinterpret_cast<float4*>(ws)[u] =
                reinterpret_cast<const float4*>(W2)[(size_t)(c * BK + krow) * 64 + nh * 32 + cc];
        }
        __syncthreads();

#pragma unroll
        for (int kk = 0; kk < 8; ++kk) {
            float4 av[5];
#pragma unroll
            for (int r = 0; r < 5; ++r)
                av[r] = reinterpret_cast<const float4*>(xs)[(5 * tm + r) * 8 + kk];
#pragma unroll
            for (int j = 0; j < 4; ++j) {
                const float4 w = reinterpret_cast<const float4*>(ws)[(kk * 4 + j) * 32 + tn];
#pragma unroll
                for (int r = 0; r < 5; ++r) {
                    const float a = (j == 0) ? av[r].x : (j == 1) ? av[r].y
                                  : (j == 2) ? av[r].z : av[r].w;
                    acc[r].x = fmaf(a, w.x, acc[r].x);
                    acc[r].y = fmaf(a, w.y, acc[r].y);
                    acc[r].z = fmaf(a, w.z, acc[r].z);
                    acc[r].w = fmaf(a, w.w, acc[r].w);
                }
            }
        }
    }

    float4 s4 = make_float4(0.f, 0.f, 0.f, 0.f), q4 = s4;
#pragma unroll
    for (int r = 0; r < 5; ++r) {
        const int row = row0 + 5 * tm + r;
        reinterpret_cast<float4*>(h2)[(size_t)row * 64 + nh * 32 + tn] = acc[r];
        s4.x += acc[r].x; s4.y += acc[r].y; s4.z += acc[r].z; s4.w += acc[r].w;
        q4.x += acc[r].x * acc[r].x; q4.y += acc[r].y * acc[r].y;
        q4.z += acc[r].z * acc[r].z; q4.w += acc[r].w * acc[r].w;
    }
    __syncthreads();
    reinterpret_cast<float4*>(red_s)[tm * 32 + tn] = s4;
    reinterpret_cast<float4*>(red_q)[tm * 32 + tn] = q4;
    __syncthreads();
    if (tid < 128) {
        float s = 0.f;
#pragma unroll
        for (int g = 0; g < 8; ++g) s += red_s[g * 128 + tid];
        atomicAdd(&sum2[nh * 128 + tid], s);
    } else {
        const int col = tid - 128;
        float q = 0.f;
#pragma unroll
        for (int g = 0; g < 8; ++g) q += red_q[g * 128 + col];
        atomicAdd(&sq2[nh * 128 + col], q);
    }
}

// ---------------------------------------------------------------------------
// Kernel 5: out = relu(bn2(h2)); BN2 finalize fused; 4 float4/thread
// ---------------------------------------------------------------------------
__global__ __launch_bounds__(256) void bn_relu_out_k(
    const float* __restrict__ h2, const float* __restrict__ sum2,
    const float* __restrict__ sq2, const float* __restrict__ gamma2,
    const float* __restrict__ beta2, float* __restrict__ out) {
    __shared__ float sc2[DOUT];
    __shared__ float sh2[DOUT];
    const int tid = threadIdx.x;
    {
        const float nInv = 1.0f / (float)NN;
        const float mean = sum2[tid] * nInv;
        const float var = sq2[tid] * nInv - mean * mean;
        const float s = gamma2[tid] * rsqrtf(var + BN_EPS);
        sc2[tid] = s;
        sh2[tid] = beta2[tid] - mean * s;
    }
    __syncthreads();
#pragma unroll
    for (int i = 0; i < 4; ++i) {
        const int u = blockIdx.x * 1024 + i * 256 + tid;  // float4 index
        const int k4 = u & 63;
        const float4 h = reinterpret_cast<const float4*>(h2)[u];
        const float4 sc = reinterpret_cast<const float4*>(sc2)[k4];
        const float4 sh = reinterpret_cast<const float4*>(sh2)[k4];
        float4 g;
        g.x = fmaxf(fmaf(h.x, sc.x, sh.x), 0.f);
        g.y = fmaxf(fmaf(h.y, sc.y, sh.y), 0.f);
        g.z = fmaxf(fmaf(h.z, sc.z, sh.z), 0.f);
        g.w = fmaxf(fmaf(h.w, sc.w, sh.w), 0.f);
        reinterpret_cast<float4*>(out)[u] = g;
    }
}

// ---------------------------------------------------------------------------
extern "C" void kernel_launch(void* const* d_in, const int* in_sizes, int n_in,
                              void* d_out, int out_size, void* d_ws,
                              size_t ws_size, hipStream_t stream) {
    const float* x      = (const float*)d_in[0];
    const int*   ei     = (const int*)d_in[1];
    const float* W1     = (const float*)d_in[2];
    const float* b1     = (const float*)d_in[3];
    const float* gamma1 = (const float*)d_in[4];
    const float* beta1  = (const float*)d_in[5];
    const float* W2     = (const float*)d_in[6];
    const float* b2     = (const float*)d_in[7];
    const float* gamma2 = (const float*)d_in[8];
    const float* beta2  = (const float*)d_in[9];
    const int E = in_sizes[1] / 2;

    // ws layout (bytes):
    // [stats 8192][hist_g NB*NN*4][offsets 40064][total 40064]
    // [edge_src 4E][xb NN*DIN*2][xin NN*DIN*2][h1 NN*DOUT*4][h2 NN*DOUT*4]
    char* w = (char*)d_ws;
    float* stats   = (float*)w;
    float* sum1    = stats + 0;
    float* sq1     = stats + 256;
    float* sum2    = stats + 1024;
    float* sq2     = stats + 1280;
    int* hist_g    = (int*)(w + 8192);
    int* offsets   = (int*)(w + 8192 + (size_t)NB * NN * 4);
    int* total     = (int*)(w + 8192 + (size_t)NB * NN * 4 + 40064);
    int* edge_src  = (int*)(w + 8192 + (size_t)NB * NN * 4 + 2 * 40064);
    ushort* xb     = (ushort*)(w + 8192 + (size_t)NB * NN * 4 + 2 * 40064 + (size_t)E * 4);
    ushort* xin    = xb + (size_t)NN * DIN;
    float* h1      = (float*)(xin + (size_t)NN * DIN);
    float* h2      = h1 + (size_t)NN * DOUT;
    float* out     = (float*)d_out;

    xcast_k<<<NN * DIN / 4 / 256 + 1, 256, 0, stream>>>(x, xb);
    khist<<<NB, 256, 0, stream>>>(ei, hist_g, E);
    kscan_a<<<40, 256, 0, stream>>>(hist_g, total);
    kscan_b<<<1, 1024, 0, stream>>>(total, offsets, stats);
    kfill<<<NB, 256, 0, stream>>>(ei, hist_g, offsets, edge_src, E);
    aggregate_k<<<NN / 8, 256, 0, stream>>>(x, xb, offsets, edge_src, xin);
    gemm1_k<<<2 * NN / BM, 256, 0, stream>>>(xin, W1, b1, h1, sum1, sq1);
    gemm2_k<<<2 * NN / BM, 256, 0, stream>>>(h1, sum1, sq1, gamma1, beta1, W2,
                                             b2, h2, sum2, sq2);
    bn_relu_out_k<<<NN * DOUT / 4 / 1024, 256, 0, stream>>>(h2, sum2, sq2,
                                                            gamma2, beta2, out);
}

// Round 10
// 89.150 us; speedup vs baseline: 2.8687x; 1.4387x over previous
//
#include <hip/hip_runtime.h>

#define NN 10000
#define DIN 128
#define DOUT 256
#define NB 128           // CSR-build blocks
static constexpr float BN_EPS = 1e-5f;

using short8 = __attribute__((ext_vector_type(8))) short;
using f32x4  = __attribute__((ext_vector_type(4))) float;

__device__ __forceinline__ unsigned short bf16r(float f) {
    unsigned int u = __float_as_uint(f);
    u += 0x7FFFu + ((u >> 16) & 1u);
    return (unsigned short)(u >> 16);
}
__device__ __forceinline__ float bf16f(unsigned short h) {
    return __uint_as_float((unsigned int)h << 16);
}
// fragment-order index for W[k][n] (K x 256), 16x16x32 MFMA B-operand.
// chunk=k>>5, panel=n>>4, lane-slot=((k>>3)&3)*16 + (n&15), j=k&7.
// NOTE: the (k-slot -> k) map only needs to be CONSISTENT between A and B
// placements (sum over slots is permutation-invariant); row/col = lane&15
// and the C/D map are the HW-verified parts.
__device__ __forceinline__ int fragidx(int k, int n) {
    return ((k >> 5) << 13) | ((n >> 4) << 9) |
           ((((k >> 3) & 3) << 4 | (n & 15)) << 3) | (k & 7);
}

// ---------------------------------------------------------------------------
// Kernel H+P: blocks 0..NB-1 = degree histogram; blocks NB..2NB-1 = prep
// (x->xb bf16, W1/W2 -> frag-ordered bf16, zero striped BN stats)
// ---------------------------------------------------------------------------
__global__ __launch_bounds__(256) void khist_prep(
    const int* __restrict__ ei, int* __restrict__ hist_g, int E,
    const float* __restrict__ x, ushort* __restrict__ xb,
    const float* __restrict__ W1, ushort* __restrict__ w1f,
    const float* __restrict__ W2, ushort* __restrict__ w2f,
    float* __restrict__ stats) {
    const int tid = threadIdx.x;
    if (blockIdx.x < NB) {
        __shared__ int hist[NN];
        for (int i = tid; i < NN; i += 256) hist[i] = 0;
        __syncthreads();
        const int chunk = (E + NB - 1) / NB;
        const int e0 = blockIdx.x * chunk;
        const int e1 = min(e0 + chunk, E);
        for (int e = e0 + tid; e < e1; e += 256) {
            atomicAdd(&hist[ei[E + e]], 1);
        }
        __syncthreads();
        int* dst = hist_g + (size_t)blockIdx.x * NN;
        for (int i = tid; i < NN; i += 256) dst[i] = hist[i];
    } else {
        const int pt = (blockIdx.x - NB) * 256 + tid;  // 0..32767
        if (pt < 8192) stats[pt] = 0.f;                // striped sums/sqs
        for (int i = pt; i < NN * DIN / 4; i += 32768) {
            const float4 v = reinterpret_cast<const float4*>(x)[i];
            ushort4 o;
            o.x = bf16r(v.x); o.y = bf16r(v.y);
            o.z = bf16r(v.z); o.w = bf16r(v.w);
            reinterpret_cast<ushort4*>(xb)[i] = o;
        }
        {   // W1: 128*256 = 32768, exactly one per thread
            const int k = pt >> 8, n = pt & 255;
            w1f[fragidx(k, n)] = bf16r(W1[pt]);
        }
        for (int i = pt; i < 256 * 256; i += 32768) {
            const int k = i >> 8, n = i & 255;
            w2f[fragidx(k, n)] = bf16r(W2[i]);
        }
    }
}

// ---------------------------------------------------------------------------
// Kernel Sa: exclusive scan of hist_g along block axis; total[node]
// ---------------------------------------------------------------------------
__global__ __launch_bounds__(256) void kscan_a(int* __restrict__ hist_g,
                                               int* __restrict__ total) {
    const int node = blockIdx.x * 256 + threadIdx.x;
    if (node >= NN) return;
    int run = 0;
#pragma unroll 8
    for (int b = 0; b < NB; ++b) {
        const int v = hist_g[(size_t)b * NN + node];
        hist_g[(size_t)b * NN + node] = run;
        run += v;
    }
    total[node] = run;
}

// ---------------------------------------------------------------------------
// Kernel Sb: single-block exclusive scan (total -> offsets)
// ---------------------------------------------------------------------------
__global__ __launch_bounds__(1024) void kscan_b(const int* __restrict__ total,
                                                int* __restrict__ offsets) {
    __shared__ int part[1024];
    const int t = threadIdx.x;
    const int base = t * 10;
    int local[10];
    int s = 0;
#pragma unroll
    for (int k = 0; k < 10; ++k) {
        const int i = base + k;
        const int v = (i < NN) ? total[i] : 0;
        local[k] = s;
        s += v;
    }
    part[t] = s;
    __syncthreads();
    for (int off = 1; off < 1024; off <<= 1) {
        int v = 0;
        if (t >= off) v = part[t - off];
        __syncthreads();
        if (t >= off) part[t] += v;
        __syncthreads();
    }
    const int prefix = (t == 0) ? 0 : part[t - 1];
#pragma unroll
    for (int k = 0; k < 10; ++k) {
        const int i = base + k;
        if (i < NN) offsets[i] = prefix + local[k];
    }
    if (t == 1023) offsets[NN] = part[1023];
}

// ---------------------------------------------------------------------------
// Kernel F: CSR fill, LDS cursor, LDS atomics
// ---------------------------------------------------------------------------
__global__ __launch_bounds__(256) void kfill(const int* __restrict__ ei,
                                             const int* __restrict__ hist_g,
                                             const int* __restrict__ offsets,
                                             int* __restrict__ edge_src,
                                             int E) {
    __shared__ int cur[NN];
    const int tid = threadIdx.x;
    const int* base = hist_g + (size_t)blockIdx.x * NN;
    for (int i = tid; i < NN; i += 256) cur[i] = base[i] + offsets[i];
    __syncthreads();
    const int chunk = (E + NB - 1) / NB;
    const int e0 = blockIdx.x * chunk;
    const int e1 = min(e0 + chunk, E);
    for (int e = e0 + tid; e < e1; e += 256) {
        const int src = ei[e];
        const int dst = ei[E + e];
        const int pos = atomicAdd(&cur[dst], 1);
        edge_src[pos] = src;
    }
}

// ---------------------------------------------------------------------------
// Kernel A: gather-aggregate bf16; writes xin directly in A-FRAGMENT order:
// xinf[mtile][c][(kg*16+row)*16B + half*8B], mtile=node>>4, row=node&15
// lane c4 holds dims [4*c4,4*c4+4): c=c4>>3, kg=(c4>>1)&3, half=c4&1
// ---------------------------------------------------------------------------
__global__ __launch_bounds__(256) void aggregate_k(
    const float* __restrict__ x, const ushort* __restrict__ xb,
    const int* __restrict__ offsets, const int* __restrict__ edge_src,
    ushort* __restrict__ xinf) {
    const int node = blockIdx.x * 8 + (threadIdx.x >> 5);
    const int c4 = threadIdx.x & 31;
    const int beg = offsets[node];
    const int end = offsets[node + 1];
    const ushort4* xb4 = reinterpret_cast<const ushort4*>(xb);

    float4 a0 = make_float4(0.f, 0.f, 0.f, 0.f);
    float4 a1 = a0, a2 = a0, a3 = a0;
    int j = beg;
    for (; j + 7 < end; j += 8) {
        int s[8];
#pragma unroll
        for (int t = 0; t < 8; ++t) s[t] = edge_src[j + t];
        ushort4 v[8];
#pragma unroll
        for (int t = 0; t < 8; ++t) v[t] = xb4[(size_t)s[t] * 32 + c4];
#pragma unroll
        for (int t = 0; t < 8; ++t) {
            float4* a = (t & 3) == 0 ? &a0 : (t & 3) == 1 ? &a1
                      : (t & 3) == 2 ? &a2 : &a3;
            a->x += bf16f(v[t].x);
            a->y += bf16f(v[t].y);
            a->z += bf16f(v[t].z);
            a->w += bf16f(v[t].w);
        }
    }
    for (; j < end; ++j) {
        const ushort4 v = xb4[(size_t)edge_src[j] * 32 + c4];
        a0.x += bf16f(v.x); a0.y += bf16f(v.y);
        a0.z += bf16f(v.z); a0.w += bf16f(v.w);
    }
    const float4 xv =
        reinterpret_cast<const float4*>(x)[(size_t)node * 32 + c4];
    ushort4 o;
    o.x = bf16r(xv.x + a0.x + a1.x + a2.x + a3.x);
    o.y = bf16r(xv.y + a0.y + a1.y + a2.y + a3.y);
    o.z = bf16r(xv.z + a0.z + a1.z + a2.z + a3.z);
    o.w = bf16r(xv.w + a0.w + a1.w + a2.w + a3.w);
    const int mt = node >> 4, row = node & 15;
    const int c = c4 >> 3, kg = (c4 >> 1) & 3, half = c4 & 1;
    *reinterpret_cast<ushort4*>(
        (char*)xinf + (size_t)mt * 4096 + c * 1024 +
        ((kg << 4) + row) * 16 + half * 8) = o;
}

// ---------------------------------------------------------------------------
// MFMA GEMM1: h1 = xin @ W1 + b1 (bf16 in, fp32 acc) + striped BN1 sums.
// 625 blocks x 16 rows; 4 waves, wave w covers cols [64w,64w+64) (4 panels).
// BN red buffer indexed by ROW-GROUP (l>>4) only: 4 x 256, each slot written
// exactly once (this was the round-9 bug: stale groups polluted BN stats).
// ---------------------------------------------------------------------------
__global__ __launch_bounds__(256) void gemm1_k(
    const ushort* __restrict__ xinf, const ushort* __restrict__ w1f,
    const float* __restrict__ b1, ushort* __restrict__ h1f,
    float* __restrict__ sum1, float* __restrict__ sq1) {
    __shared__ short a_lds[4 * 64 * 8];   // 4KB, all 4 k-chunks
    __shared__ float work[6208];          // b_chunk(4096) | hrow(4160)+red(2048)
    short* b_lds = (short*)work;
    float* hrow  = work;                  // 16 x 260, valid after main loop
    float* red_s = work + 4160;           // 4 x 256
    float* red_q = work + 5184;           // 4 x 256
    const int tid = threadIdx.x;
    const int w = tid >> 6, l = tid & 63;
    const int m = blockIdx.x;

    // stage A (coalesced copy, already fragment-ordered by aggregate)
    ((float4*)a_lds)[tid] = ((const float4*)xinf)[m * 256 + tid];

    f32x4 acc[4];
#pragma unroll
    for (int p = 0; p < 4; ++p) {
        const float b = b1[(w * 4 + p) * 16 + (l & 15)];
        acc[p] = (f32x4){b, b, b, b};
    }

    for (int c = 0; c < 4; ++c) {
        __syncthreads();
        const float4* src = ((const float4*)w1f) + c * 1024;
#pragma unroll
        for (int i = 0; i < 4; ++i)
            ((float4*)b_lds)[tid + 256 * i] = src[tid + 256 * i];
        __syncthreads();
        const short8 a = ((const short8*)a_lds)[c * 64 + l];
#pragma unroll
        for (int p = 0; p < 4; ++p) {
            const short8 b = ((const short8*)b_lds)[(w * 4 + p) * 64 + l];
            acc[p] = __builtin_amdgcn_mfma_f32_16x16x32_bf16(a, b, acc[p],
                                                             0, 0, 0);
        }
    }
    __syncthreads();

    // D -> hrow (row-major, stride 260) + per-row-group column partials
#pragma unroll
    for (int p = 0; p < 4; ++p) {
        const int col = (w * 4 + p) * 16 + (l & 15);
        float s = 0.f, q = 0.f;
#pragma unroll
        for (int r = 0; r < 4; ++r) {
            const float v = acc[p][r];
            hrow[((l >> 4) * 4 + r) * 260 + col] = v;
            s += v;
            q += v * v;
        }
        red_s[(l >> 4) * 256 + col] = s;
        red_q[(l >> 4) * 256 + col] = q;
    }
    __syncthreads();
    {
        float s = 0.f, q = 0.f;
#pragma unroll
        for (int g = 0; g < 4; ++g) {
            s += red_s[g * 256 + tid];
            q += red_q[g * 256 + tid];
        }
        atomicAdd(&sum1[(m & 7) * 256 + tid], s);
        atomicAdd(&sq1[(m & 7) * 256 + tid], q);
    }
    // h1f write: 512 frags (gemm2 A order), 2 per thread
#pragma unroll
    for (int t = 0; t < 2; ++t) {
        const int u = tid + t * 256;
        const int c2 = u >> 6, kg = (u >> 4) & 3, row = u & 15;
        const float* src = &hrow[row * 260 + c2 * 32 + kg * 8];
        short8 g;
#pragma unroll
        for (int jj = 0; jj < 8; ++jj) g[jj] = (short)bf16r(src[jj]);
        ((short8*)h1f)[m * 512 + u] = g;
    }
}

// ---------------------------------------------------------------------------
// MFMA GEMM2: h2 = relu(bn1(h1)) @ W2 + b2 + striped BN2 sums.
// BN1 finalize fused (striped sums). h2 written row-major fp32.
// ---------------------------------------------------------------------------
__global__ __launch_bounds__(256) void gemm2_k(
    const ushort* __restrict__ h1f, const float* __restrict__ sum1,
    const float* __restrict__ sq1, const float* __restrict__ gamma1,
    const float* __restrict__ beta1, const ushort* __restrict__ w2f,
    const float* __restrict__ b2, float* __restrict__ h2,
    float* __restrict__ sum2, float* __restrict__ sq2) {
    __shared__ short a_lds[8 * 64 * 8];   // 8KB
    __shared__ float work[6208];
    __shared__ float sc1[DOUT], sh1[DOUT];
    short* b_lds = (short*)work;
    float* hrow  = work;
    float* red_s = work + 4160;
    float* red_q = work + 5184;
    const int tid = threadIdx.x;
    const int w = tid >> 6, l = tid & 63;
    const int m = blockIdx.x;

    {   // BN1 finalize from striped sums
        float s = 0.f, q = 0.f;
#pragma unroll
        for (int i = 0; i < 8; ++i) {
            s += sum1[i * 256 + tid];
            q += sq1[i * 256 + tid];
        }
        const float nInv = 1.0f / (float)NN;
        const float mean = s * nInv;
        const float var = q * nInv - mean * mean;
        const float sc = gamma1[tid] * rsqrtf(var + BN_EPS);
        sc1[tid] = sc;
        sh1[tid] = beta1[tid] - mean * sc;
    }
    __syncthreads();

    // stage A with fused bn1+relu (coalesced 16B frag reads)
#pragma unroll
    for (int t = 0; t < 2; ++t) {
        const int u = tid + 256 * t;
        const int col0 = ((u >> 6) << 5) + (((u >> 4) & 3) << 3);
        const short8 hv = ((const short8*)h1f)[m * 512 + u];
        short8 g;
#pragma unroll
        for (int jj = 0; jj < 8; ++jj) {
            const float f = bf16f((unsigned short)hv[jj]);
            const float r = fmaxf(fmaf(f, sc1[col0 + jj], sh1[col0 + jj]), 0.f);
            g[jj] = (short)bf16r(r);
        }
        ((short8*)a_lds)[u] = g;
    }

    f32x4 acc[4];
#pragma unroll
    for (int p = 0; p < 4; ++p) {
        const float b = b2[(w * 4 + p) * 16 + (l & 15)];
        acc[p] = (f32x4){b, b, b, b};
    }

    for (int c = 0; c < 8; ++c) {
        __syncthreads();
        const float4* src = ((const float4*)w2f) + c * 1024;
#pragma unroll
        for (int i = 0; i < 4; ++i)
            ((float4*)b_lds)[tid + 256 * i] = src[tid + 256 * i];
        __syncthreads();
        const short8 a = ((const short8*)a_lds)[c * 64 + l];
#pragma unroll
        for (int p = 0; p < 4; ++p) {
            const short8 b = ((const short8*)b_lds)[(w * 4 + p) * 64 + l];
            acc[p] = __builtin_amdgcn_mfma_f32_16x16x32_bf16(a, b, acc[p],
                                                             0, 0, 0);
        }
    }
    __syncthreads();

#pragma unroll
    for (int p = 0; p < 4; ++p) {
        const int col = (w * 4 + p) * 16 + (l & 15);
        float s = 0.f, q = 0.f;
#pragma unroll
        for (int r = 0; r < 4; ++r) {
            const float v = acc[p][r];
            hrow[((l >> 4) * 4 + r) * 260 + col] = v;
            s += v;
            q += v * v;
        }
        red_s[(l >> 4) * 256 + col] = s;
        red_q[(l >> 4) * 256 + col] = q;
    }
    __syncthreads();
    {
        float s = 0.f, q = 0.f;
#pragma unroll
        for (int g = 0; g < 4; ++g) {
            s += red_s[g * 256 + tid];
            q += red_q[g * 256 + tid];
        }
        atomicAdd(&sum2[(m & 7) * 256 + tid], s);
        atomicAdd(&sq2[(m & 7) * 256 + tid], q);
    }
    // h2 row-major fp32 (coalesced)
#pragma unroll
    for (int i = 0; i < 4; ++i) {
        const int idx = tid + 256 * i;            // 1024 float4
        const int row = idx >> 6, col4 = idx & 63;
        const float4 v = *(const float4*)&hrow[row * 260 + col4 * 4];
        ((float4*)h2)[(size_t)(m * 16 + row) * 64 + col4] = v;
    }
}

// ---------------------------------------------------------------------------
// Kernel 5: out = relu(bn2(h2)); BN2 finalize (striped) fused
// ---------------------------------------------------------------------------
__global__ __launch_bounds__(256) void bn_relu_out_k(
    const float* __restrict__ h2, const float* __restrict__ sum2,
    const float* __restrict__ sq2, const float* __restrict__ gamma2,
    const float* __restrict__ beta2, float* __restrict__ out) {
    __shared__ float sc2[DOUT], sh2[DOUT];
    const int tid = threadIdx.x;
    {
        float s = 0.f, q = 0.f;
#pragma unroll
        for (int i = 0; i < 8; ++i) {
            s += sum2[i * 256 + tid];
            q += sq2[i * 256 + tid];
        }
        const float nInv = 1.0f / (float)NN;
        const float mean = s * nInv;
        const float var = q * nInv - mean * mean;
        const float sc = gamma2[tid] * rsqrtf(var + BN_EPS);
        sc2[tid] = sc;
        sh2[tid] = beta2[tid] - mean * sc;
    }
    __syncthreads();
#pragma unroll
    for (int i = 0; i < 4; ++i) {
        const int u = blockIdx.x * 1024 + i * 256 + tid;
        const int k4 = u & 63;
        const float4 h = reinterpret_cast<const float4*>(h2)[u];
        const float4 sc = reinterpret_cast<const float4*>(sc2)[k4];
        const float4 sh = reinterpret_cast<const float4*>(sh2)[k4];
        float4 g;
        g.x = fmaxf(fmaf(h.x, sc.x, sh.x), 0.f);
        g.y = fmaxf(fmaf(h.y, sc.y, sh.y), 0.f);
        g.z = fmaxf(fmaf(h.z, sc.z, sh.z), 0.f);
        g.w = fmaxf(fmaf(h.w, sc.w, sh.w), 0.f);
        reinterpret_cast<float4*>(out)[u] = g;
    }
}

// ---------------------------------------------------------------------------
extern "C" void kernel_launch(void* const* d_in, const int* in_sizes, int n_in,
                              void* d_out, int out_size, void* d_ws,
                              size_t ws_size, hipStream_t stream) {
    const float* x      = (const float*)d_in[0];
    const int*   ei     = (const int*)d_in[1];
    const float* W1     = (const float*)d_in[2];
    const float* b1     = (const float*)d_in[3];
    const float* gamma1 = (const float*)d_in[4];
    const float* beta1  = (const float*)d_in[5];
    const float* W2     = (const float*)d_in[6];
    const float* b2     = (const float*)d_in[7];
    const float* gamma2 = (const float*)d_in[8];
    const float* beta2  = (const float*)d_in[9];
    const int E = in_sizes[1] / 2;

    char* w = (char*)d_ws;
    size_t off = 0;
    float* stats = (float*)(w + off); off += 32768;  // 8192 floats (striped)
    float* sum1 = stats + 0;
    float* sq1  = stats + 2048;
    float* sum2 = stats + 4096;
    float* sq2  = stats + 6144;
    int* hist_g   = (int*)(w + off); off += (size_t)NB * NN * 4;
    int* offsets  = (int*)(w + off); off += 40064;
    int* total    = (int*)(w + off); off += 40064;
    int* edge_src = (int*)(w + off); off += (size_t)E * 4;
    ushort* xb    = (ushort*)(w + off); off += (size_t)NN * DIN * 2;
    ushort* xinf  = (ushort*)(w + off); off += (size_t)NN * DIN * 2;
    ushort* w1f   = (ushort*)(w + off); off += 65536;
    ushort* w2f   = (ushort*)(w + off); off += 131072;
    ushort* h1f   = (ushort*)(w + off); off += (size_t)NN * DOUT * 2;
    float* h2     = (float*)(w + off); off += (size_t)NN * DOUT * 4;
    float* out    = (float*)d_out;

    khist_prep<<<2 * NB, 256, 0, stream>>>(ei, hist_g, E, x, xb, W1, w1f,
                                           W2, w2f, stats);
    kscan_a<<<40, 256, 0, stream>>>(hist_g, total);
    kscan_b<<<1, 1024, 0, stream>>>(total, offsets);
    kfill<<<NB, 256, 0, stream>>>(ei, hist_g, offsets, edge_src, E);
    aggregate_k<<<NN / 8, 256, 0, stream>>>(x, xb, offsets, edge_src, xinf);
    gemm1_k<<<NN / 16, 256, 0, stream>>>(xinf, w1f, b1, h1f, sum1, sq1);
    gemm2_k<<<NN / 16, 256, 0, stream>>>(h1f, sum1, sq1, gamma1, beta1, w2f,
                                         b2, h2, sum2, sq2);
    bn_relu_out_k<<<NN * DOUT / 4 / 1024, 256, 0, stream>>>(h2, sum2, sq2,
                                                            gamma2, beta2, out);
}